// Round 10
// baseline (1284.616 us; speedup 1.0000x reference)
//
#include <hip/hip_runtime.h>
#include <math.h>

// ---------------------------------------------------------------------------
// Model constants
// ---------------------------------------------------------------------------
#define Bn   64
#define Nn   256
#define Ln   2048
#define CMP  128
#define PROT 128
#define GF   64
#define NHEADS 4
#define LT   128
#define DOUT 386   // 3*LATENT + 2
#define CB   32    // batch chunk (CNN staging)
#define NCH  (Bn / CB)
#define FLSP 4     // bidat_fused l-split

typedef unsigned short u16;
typedef unsigned long long u64;
typedef __attribute__((ext_vector_type(8))) short short8v;   // 8 bf16 (4 VGPRs)
typedef __attribute__((ext_vector_type(4))) float f32x4;
typedef __attribute__((ext_vector_type(4))) unsigned short u16x4;
typedef __attribute__((ext_vector_type(4))) unsigned int u32x4;

#define MFMA(a, b, c) __builtin_amdgcn_mfma_f32_16x16x32_bf16((a), (b), (c), 0, 0, 0)

__device__ __forceinline__ float apply_act(float v, int act) {
  if (act == 1) return v > 0.f ? v : 0.2f * v;   // lrelu ALPHA
  if (act == 2) return v > 0.f ? v : 0.1f * v;   // lrelu 0.1 (fingerprint)
  if (act == 3) return tanhf(v);
  return v;
}

__device__ __forceinline__ u16 bfc(float f) {    // fp32 -> bf16 RNE
  union { float f; unsigned u; } x; x.f = f;
  unsigned r = x.u + 0x7fffu + ((x.u >> 16) & 1u);
  return (u16)(r >> 16);
}

__device__ __forceinline__ float bf2f(u16 h) {
  union { unsigned u; float f; } x; x.u = ((unsigned)h) << 16; return x.f;
}

// fast tanh: 1 - 2*rcp(2^(2*log2e*x)+1); HW exp2+rcp, ~1e-6 abs err, saturates
__device__ __forceinline__ float ftanh(float x) {
  float e = __builtin_amdgcn_exp2f(x * 2.885390081777927f);
  return 1.f - 2.f * __builtin_amdgcn_rcpf(e + 1.f);
}

// byte offset into a [R][C] bf16 LDS tile, XOR-swizzled (r7-validated: 0 conflicts)
template<int C>
__device__ __forceinline__ int lofs(int r, int c) {
  if (C == 256) return ((r * C + c) * 2) ^ ((r & 15) << 4);
  if (C == 128) return ((r * C + c) * 2) ^ ((r & 15) << 4);
  return ((r * C + c) * 2) ^ ((r & 7) << 4);
}

__device__ __forceinline__ short8v ldsv(const u16* s, int byteofs) {
  return *(const short8v*)((const char*)s + byteofs);
}

// ---------------------------------------------------------------------------
// Embedding gather (atoms only)
// ---------------------------------------------------------------------------
__global__ void embed_kernel(const int* __restrict__ idx, const float* __restrict__ E,
                             float* __restrict__ out, long total, int C) {
  long i = (long)blockIdx.x * blockDim.x + threadIdx.x;
  if (i >= total) return;
  long r = i / C;
  int c = (int)(i - r * (long)C);
  out[i] = E[(long)idx[r] * C + c];
}

__global__ void zero_kernel(float* __restrict__ a, long n) {
  long i = (long)blockIdx.x * blockDim.x + threadIdx.x;
  if (i < n) a[i] = 0.f;
}

// adjacency -> bitmask [NB rows][4 u64]
__global__ void packadj_kernel(const int* __restrict__ adj, u64* __restrict__ adjb) {
  long idx = (long)blockIdx.x * 256 + threadIdx.x;
  int lane = threadIdx.x & 63;
  bool bit = adj[idx] > 0;
  u64 m = __ballot(bit);
  if (lane == 0) adjb[idx >> 6] = m;
}

// ---------------------------------------------------------------------------
// Weight prep: dst[z][n*K + k] = bf16(src[z][k*N + n])
// ---------------------------------------------------------------------------
__global__ void transp_kernel(const float* __restrict__ src, u16* __restrict__ dst,
                              int K, int N) {
  long total = (long)K * N;
  long base = (long)blockIdx.y * total;
  long idx = (long)blockIdx.x * 256 + threadIdx.x;
  if (idx >= total) return;
  int k = (int)(idx % K);
  int n = (int)(idx / K);
  dst[base + idx] = bfc(src[base + (long)k * N + n]);
}

struct Ptr8 { const float* p[8]; };
__global__ void transp8_kernel(Ptr8 srcs, u16* __restrict__ dst) {
  int y = blockIdx.y;
  int idx = blockIdx.x * 256 + threadIdx.x;   // 0..16383
  int k = idx & 127, n = idx >> 7;
  dst[(long)y * 16384 + idx] = bfc(srcs.p[y][k * 128 + n]);
}

// ---------------------------------------------------------------------------
// bf16 activation transpose: in [NB][C] -> out [b][C][Nn] (LDS-tiled, coalesced)
// grid (C/64, Nn/64, Bn), 256 threads
// ---------------------------------------------------------------------------
__global__ __launch_bounds__(256) void transpT_kernel(
    const u16* __restrict__ in, u16* __restrict__ out, int C)
{
  __shared__ u16 sT[64 * 64];
  int c0 = blockIdx.x * 64, r0 = blockIdx.y * 64, b = blockIdx.z;
  int tid = threadIdx.x;
  for (int q = tid; q < 512; q += 256) {
    int r = q >> 3, c8 = (q & 7) << 3;
    *(u32x4*)((char*)sT + lofs<64>(r, c8)) =
        *(const u32x4*)(in + ((long)b * Nn + r0 + r) * C + c0 + c8);
  }
  __syncthreads();
  int c = tid >> 2, r8 = (tid & 3) << 4;
  u16 tmp[16];
#pragma unroll
  for (int j = 0; j < 16; ++j)
    tmp[j] = *(const u16*)((char*)sT + lofs<64>(r8 + j, c));
  long ob = ((long)b * C + c0 + c) * 256 + r0 + r8;
  *(u32x4*)(out + ob) = *(u32x4*)tmp;
  *(u32x4*)(out + ob + 8) = *(u32x4*)(tmp + 8);
}

// wv[0,1024): gat head vectors w[h][which][128]; wv[1024,1536): go vectors [2][256]
__global__ void wvec_kernel(const float* __restrict__ gatW, const float* __restrict__ gatA,
                            const float* __restrict__ goW, const float* __restrict__ goA,
                            float* __restrict__ wv) {
  int idx = blockIdx.x * 256 + threadIdx.x;
  if (idx < 1024) {
    int h = idx >> 8, wq = (idx >> 7) & 1, d = idx & 127;
    const float* W = gatW + ((long)h * 128 + d) * 64;
    const float* a = gatA + h * 128 + wq * 64;
    float s = 0.f;
    for (int f = 0; f < 64; ++f) s += W[f] * a[f];
    wv[idx] = s;
  } else if (idx < 1536) {
    int k = idx - 1024; int wq = k >> 8, d = k & 255;
    const float* W = goW + (long)d * 128;
    const float* a = goA + wq * 128;
    float s = 0.f;
    for (int f = 0; f < 128; ++f) s += W[f] * a[f];
    wv[idx] = s;
  }
}

// f1/f2 for 4 heads from AVE: one wave per row
__global__ __launch_bounds__(256) void favv_kernel(
    const float* __restrict__ AVE, const float* __restrict__ wv,
    float* __restrict__ f1, float* __restrict__ f2, long rows)
{
  __shared__ float w[1024];
  int tid = threadIdx.x;
  for (int q = tid; q < 1024; q += 256) w[q] = wv[q];
  __syncthreads();
  long r = (long)blockIdx.x * 4 + (tid >> 6);
  int lane = tid & 63;
  float a0 = AVE[r * 128 + lane], a1 = AVE[r * 128 + 64 + lane];
#pragma unroll
  for (int h = 0; h < 4; ++h) {
    float s1 = a0 * w[h * 256 + lane] + a1 * w[h * 256 + 64 + lane];
    float s2 = a0 * w[h * 256 + 128 + lane] + a1 * w[h * 256 + 192 + lane];
#pragma unroll
    for (int m = 32; m; m >>= 1) { s1 += __shfl_xor(s1, m, 64); s2 += __shfl_xor(s2, m, 64); }
    if (lane == 0) { f1[(long)h * rows + r] = s1; f2[(long)h * rows + r] = s2; }
  }
}

// f1/f2 from MH [rows][256] with gv = wv+1024
__global__ __launch_bounds__(256) void fmh_kernel(
    const float* __restrict__ MH, const float* __restrict__ gv,
    float* __restrict__ f1, float* __restrict__ f2, long rows)
{
  __shared__ float w[512];
  int tid = threadIdx.x;
  for (int q = tid; q < 512; q += 256) w[q] = gv[q];
  __syncthreads();
  long r = (long)blockIdx.x * 4 + (tid >> 6);
  int lane = tid & 63;
  const float* m = MH + r * 256;
  float s1 = 0.f, s2 = 0.f;
#pragma unroll
  for (int t = 0; t < 4; ++t) {
    float a = m[t * 64 + lane];
    s1 += a * w[t * 64 + lane];
    s2 += a * w[256 + t * 64 + lane];
  }
#pragma unroll
  for (int mm = 32; mm; mm >>= 1) { s1 += __shfl_xor(s1, mm, 64); s2 += __shfl_xor(s2, mm, 64); }
  if (lane == 0) { f1[r] = s1; f2[r] = s2; }
}

// ---------------------------------------------------------------------------
// pack bvec/aw/ab for mmdot (r6-validated)
// ---------------------------------------------------------------------------
__global__ void pack_kernel(
    const float* __restrict__ bh_c_b, const float* __restrict__ t_c2p_b,
    const float* __restrict__ ba_c_w, const float* __restrict__ ba_c_b,
    const float* __restrict__ ba_p_w, const float* __restrict__ bh_p_b,
    const float* __restrict__ t_p2c_b, const float* __restrict__ ba_p_b,
    float* __restrict__ pk_a, float* __restrict__ pk_p)
{
  int idx = blockIdx.x * 256 + threadIdx.x;
  if (idx < 1024) {
    int g = idx >> 7, j = idx & 127;
    pk_a[idx] = g < 4 ? bh_c_b[g * 128 + j] : t_c2p_b[(g - 4) * 128 + j];
    pk_p[idx] = g < 4 ? bh_p_b[g * 128 + j] : t_p2c_b[(g - 4) * 128 + j];
  } else if (idx < 2048) {
    int k = idx - 1024; int g = k >> 7, j = k & 127;
    pk_a[idx] = g < 4 ? ba_c_w[g * 256 + j] : ba_p_w[(g - 4) * 256 + 128 + j];
    pk_p[idx] = g < 4 ? ba_p_w[g * 256 + j] : ba_c_w[(g - 4) * 256 + 128 + j];
  } else if (idx < 2056) {
    int g = idx - 2048;
    pk_a[idx] = g < 4 ? ba_c_b[g] : 0.f;
    pk_p[idx] = g < 4 ? ba_p_b[g] : 0.f;
  }
}

// ---------------------------------------------------------------------------
// MFMA GEMM: C = act(A @ B + bias).  A fp32 [M,K], Bt bf16 [N,K].
// OUT=0: fp32 C[row*ldc+colOff+col];  OUT=1: bf16 C[row*ldc+col]
// ---------------------------------------------------------------------------
template<int ACT, int OUT>
__global__ __launch_bounds__(256) void mfma_mm_kernel(
    const float* __restrict__ A, const u16* __restrict__ Bt,
    const float* __restrict__ bias, void* __restrict__ Cp,
    int M, int N, int K, int lda, int ldc, int colOff)
{
  __shared__ u16 sA[64 * 64];
  __shared__ u16 sB[64 * 64];
  int m0 = blockIdx.y * 64, n0 = blockIdx.x * 64;
  int tid = threadIdx.x, lane = tid & 63, wv = tid >> 6;
  int mh = wv >> 1, nh = wv & 1;
  f32x4 acc00 = {0.f,0.f,0.f,0.f};
  f32x4 acc01 = acc00, acc10 = acc00, acc11 = acc00;
  for (int k0 = 0; k0 < K; k0 += 64) {
#pragma unroll
    for (int q = tid; q < 64 * 16; q += 256) {
      int r = q >> 4, c4 = (q & 15) << 2;
      float4 v = *(const float4*)(A + (long)(m0 + r) * lda + k0 + c4);
      u16x4 h = { bfc(v.x), bfc(v.y), bfc(v.z), bfc(v.w) };
      *(u16x4*)((char*)sA + lofs<64>(r, c4)) = h;
    }
#pragma unroll
    for (int q = tid; q < 64 * 8; q += 256) {
      int r = q >> 3, c8 = (q & 7) << 3;
      *(u32x4*)((char*)sB + lofs<64>(r, c8)) =
          *(const u32x4*)(Bt + (long)(n0 + r) * K + k0 + c8);
    }
    __syncthreads();
#pragma unroll
    for (int kk = 0; kk < 64; kk += 32) {
      int kf = kk + ((lane >> 4) << 3);
      short8v a0 = ldsv(sA, lofs<64>(mh * 32 + (lane & 15), kf));
      short8v a1 = ldsv(sA, lofs<64>(mh * 32 + 16 + (lane & 15), kf));
      short8v b0 = ldsv(sB, lofs<64>(nh * 32 + (lane & 15), kf));
      short8v b1 = ldsv(sB, lofs<64>(nh * 32 + 16 + (lane & 15), kf));
      acc00 = MFMA(a0, b0, acc00);
      acc01 = MFMA(a0, b1, acc01);
      acc10 = MFMA(a1, b0, acc10);
      acc11 = MFMA(a1, b1, acc11);
    }
    __syncthreads();
  }
#pragma unroll
  for (int rt = 0; rt < 2; ++rt) {
#pragma unroll
    for (int ct = 0; ct < 2; ++ct) {
      f32x4 a = rt == 0 ? (ct == 0 ? acc00 : acc01) : (ct == 0 ? acc10 : acc11);
      int col = n0 + nh * 32 + ct * 16 + (lane & 15);
      float bv = bias ? bias[col] : 0.f;
#pragma unroll
      for (int r4 = 0; r4 < 4; ++r4) {
        int row = m0 + mh * 32 + rt * 16 + ((lane >> 4) << 2) + r4;
        float v = apply_act(a[r4] + bv, ACT);
        if (OUT == 0)
          ((float*)Cp)[(long)row * ldc + colOff + col] = v;
        else
          ((u16*)Cp)[(long)row * ldc + col] = bfc(v);
      }
    }
  }
}

template<int ACT, int OUT>
static void mmx(hipStream_t st, const float* A, const u16* Bt, const float* bias,
                void* C, int M, int N, int K, int lda, int ldc, int colOff = 0)
{
  dim3 grid(N / 64, M / 64);
  mfma_mm_kernel<ACT, OUT><<<grid, dim3(256), 0, st>>>(
      A, Bt, bias, C, M, N, K, lda, ldc, colOff);
}

// ---------------------------------------------------------------------------
// mmdot v3 (T14 prefetch): out[g][row] = sum_col ftanh((X@W_g)+bv)*aw + ab
// grid (M/128, 2): y selects 4 groups; 8 W-half stages prefetched into regs.
// ---------------------------------------------------------------------------
template<int XBF>
__global__ __launch_bounds__(256) void mmdot_kernel(
    const void* __restrict__ Xp, const u16* __restrict__ Wcat,
    const float* __restrict__ pk, float* __restrict__ out, long M)
{
  __shared__ u16 sX[128 * 128];    // 32 KB
  __shared__ u16 sW[64 * 128];     // 16 KB
  __shared__ float bv_s[64], aw_s[64];
  long m0 = (long)blockIdx.x * 128;
  int g0 = blockIdx.y * 4;
  int tid = threadIdx.x, lane = tid & 63, wv = tid >> 6;
  if (XBF) {
    const u16* X = (const u16*)Xp;
    for (int q = tid; q < 128 * 16; q += 256) {
      int r = q >> 4, c8 = (q & 15) << 3;
      *(u32x4*)((char*)sX + lofs<128>(r, c8)) =
          *(const u32x4*)(X + (m0 + r) * 128 + c8);
    }
  } else {
    const float* X = (const float*)Xp;
    for (int q = tid; q < 128 * 32; q += 256) {
      int r = q >> 5, c4 = (q & 31) << 2;
      float4 v = *(const float4*)(X + (m0 + r) * 128 + c4);
      u16x4 h = { bfc(v.x), bfc(v.y), bfc(v.z), bfc(v.w) };
      *(u16x4*)((char*)sX + lofs<128>(r, c4)) = h;
    }
  }
  int rj[4], cj[4];
#pragma unroll
  for (int j = 0; j < 4; ++j) { int q = tid + j * 256; rj[j] = q >> 4; cj[j] = (q & 15) << 3; }
  u32x4 wpf[4];
  float bvp = 0.f, awp = 0.f;
  {
#pragma unroll
    for (int j = 0; j < 4; ++j)
      wpf[j] = *(const u32x4*)(Wcat + (long)g0 * 16384 + (long)rj[j] * 128 + cj[j]);
    if (tid < 64) { bvp = pk[g0 * 128 + tid]; awp = pk[1024 + g0 * 128 + tid]; }
  }
  float p[2][4];
  for (int s = 0; s < 8; ++s) {
    int gi = s >> 1, hh = s & 1, g = g0 + gi;
    if (hh == 0) {
#pragma unroll
      for (int rt = 0; rt < 2; ++rt)
#pragma unroll
        for (int r4 = 0; r4 < 4; ++r4) p[rt][r4] = 0.f;
    }
    __syncthreads();                 // sW/bv consumed by prev compute
#pragma unroll
    for (int j = 0; j < 4; ++j)
      *(u32x4*)((char*)sW + lofs<128>(rj[j], cj[j])) = wpf[j];
    if (tid < 64) { bv_s[tid] = bvp; aw_s[tid] = awp; }
    if (s < 7) {
      int s2 = s + 1, g2 = g0 + (s2 >> 1), h2 = s2 & 1;
#pragma unroll
      for (int j = 0; j < 4; ++j)
        wpf[j] = *(const u32x4*)(Wcat + (long)g2 * 16384 + (long)(h2 * 64 + rj[j]) * 128 + cj[j]);
      if (tid < 64) { bvp = pk[g2 * 128 + h2 * 64 + tid]; awp = pk[1024 + g2 * 128 + h2 * 64 + tid]; }
    }
    __syncthreads();
    for (int lt = 0; lt < 4; ++lt) {
      int col = lt * 16 + (lane & 15);
      float bv = bv_s[col], awv = aw_s[col];
#pragma unroll
      for (int rt = 0; rt < 2; ++rt) {
        f32x4 c = {0.f,0.f,0.f,0.f};
#pragma unroll
        for (int kk = 0; kk < 128; kk += 32) {
          int kf = kk + ((lane >> 4) << 3);
          short8v a = ldsv(sX, lofs<128>(wv * 32 + rt * 16 + (lane & 15), kf));
          short8v bb = ldsv(sW, lofs<128>(lt * 16 + (lane & 15), kf));
          c = MFMA(a, bb, c);
        }
#pragma unroll
        for (int r4 = 0; r4 < 4; ++r4)
          p[rt][r4] += ftanh(c[r4] + bv) * awv;
      }
    }
    if (hh == 1) {
      float ab = pk[2048 + g];
#pragma unroll
      for (int rt = 0; rt < 2; ++rt)
#pragma unroll
        for (int r4 = 0; r4 < 4; ++r4) {
          float sv = p[rt][r4];
          sv += __shfl_xor(sv, 1, 64); sv += __shfl_xor(sv, 2, 64);
          sv += __shfl_xor(sv, 4, 64); sv += __shfl_xor(sv, 8, 64);
          if ((lane & 15) == 0) {
            long row = m0 + wv * 32 + rt * 16 + ((lane >> 4) << 2) + r4;
            out[(long)g * M + row] = sv + ab;
          }
        }
    }
  }
}

// ---------------------------------------------------------------------------
// bidat_fused v4: T14 register prefetch, 64-l chunks, A-frags in registers.
// blockIdx.z = lz*4 + it.
// ---------------------------------------------------------------------------
__global__ __launch_bounds__(256) void bidat_fused(
    const u16* __restrict__ AVU4,    // [Bn*Nn][512] bf16 (4 iters concat)
    const u16* __restrict__ PVbf,    // [Bn][Ln][128] bf16
    float* __restrict__ OUTP,        // [8][Bn*Ln]: g<4 SCP, g>=4 q
    float* __restrict__ OUTA,        // [8][Bn*Nn]: g<4 SCA, g>=4 r
    const float* __restrict__ am, const float* __restrict__ pm)
{
  __shared__ u16 sK[64 * 128];       // 16 KB
  __shared__ float qm_s[64], pm_s[64], amr_s[128], am_sh[128];
  __shared__ float scp_red[4][64];
  const long NBt = (long)Bn * Nn, LBt = (long)Bn * Ln;
  int b = blockIdx.y;
  int n0 = blockIdx.x * 128;
  int zz = blockIdx.z;
  int it = zz & 3, lz = zz >> 2;
  const float* qv = OUTP + (long)(4 + it) * LBt;
  const float* rv = OUTA + (long)(4 + it) * NBt;
  float* SCA = OUTA + (long)it * NBt;
  float* SCP = OUTP + (long)it * LBt;
  int tid = threadIdx.x, lane = tid & 63, wv = tid >> 6;
  const long bLn = (long)b * Ln;

  short8v af[2][4];
  {
    long rbase = (long)b * Nn + n0 + wv * 32 + (lane & 15);
    int cbase = it * 128 + ((lane >> 4) << 3);
#pragma unroll
    for (int rt = 0; rt < 2; ++rt)
#pragma unroll
      for (int k4 = 0; k4 < 4; ++k4)
        af[rt][k4] = *(const short8v*)(AVU4 + (rbase + rt * 16) * 512 + cbase + k4 * 32);
  }
  if (tid < 128) {
    float amv = am[(long)b * Nn + n0 + tid];
    am_sh[tid] = amv;
    amr_s[tid] = amv * rv[(long)b * Nn + n0 + tid];
  }
  float sca_r[2][4] = {{0.f,0.f,0.f,0.f},{0.f,0.f,0.f,0.f}};
  const u16* pvb = PVbf + bLn * 128;
  int lbeg = lz * (Ln / FLSP);

  int rj[4], cj[4];
#pragma unroll
  for (int j = 0; j < 4; ++j) { int q = tid + j * 256; rj[j] = q >> 4; cj[j] = (q & 15) << 3; }
  u32x4 kpf[4];
  float ppm = 0.f, pqv = 0.f;
  {
#pragma unroll
    for (int j = 0; j < 4; ++j)
      kpf[j] = *(const u32x4*)(pvb + (long)(lbeg + rj[j]) * 128 + cj[j]);
    if (tid < 64) { ppm = pm[bLn + lbeg + tid]; pqv = qv[bLn + lbeg + tid]; }
  }

  for (int ci = 0; ci < (Ln / FLSP) / 64; ++ci) {
    int l0 = lbeg + ci * 64;
    __syncthreads();                       // sK / scp_red / pm_s consumed
#pragma unroll
    for (int j = 0; j < 4; ++j)
      *(u32x4*)((char*)sK + lofs<128>(rj[j], cj[j])) = kpf[j];
    if (tid < 64) { pm_s[tid] = ppm; qm_s[tid] = ppm * pqv; }
    if (ci + 1 < (Ln / FLSP) / 64) {
      int ln = l0 + 64;
#pragma unroll
      for (int j = 0; j < 4; ++j)
        kpf[j] = *(const u32x4*)(pvb + (long)(ln + rj[j]) * 128 + cj[j]);
      if (tid < 64) { ppm = pm[bLn + ln + tid]; pqv = qv[bLn + ln + tid]; }
    }
    __syncthreads();
    for (int lt = 0; lt < 4; ++lt) {
      float sp = 0.f;
      float qmv = qm_s[lt * 16 + (lane & 15)];
#pragma unroll
      for (int rt = 0; rt < 2; ++rt) {
        f32x4 c = {0.f,0.f,0.f,0.f};
#pragma unroll
        for (int k4 = 0; k4 < 4; ++k4) {
          short8v bb = ldsv(sK, lofs<128>(lt * 16 + (lane & 15),
                                          k4 * 32 + ((lane >> 4) << 3)));
          c = MFMA(af[rt][k4], bb, c);
        }
#pragma unroll
        for (int r4 = 0; r4 < 4; ++r4) {
          int nr = wv * 32 + rt * 16 + ((lane >> 4) << 2) + r4;
          float t = ftanh(c[r4]);
          sca_r[rt][r4] += t * qmv;
          sp += t * amr_s[nr];
        }
      }
      sp += __shfl_xor(sp, 16, 64);
      sp += __shfl_xor(sp, 32, 64);
      if (lane < 16) scp_red[wv][lt * 16 + lane] = sp;
    }
    __syncthreads();
    if (tid < 64) {
      float v = scp_red[0][tid] + scp_red[1][tid] + scp_red[2][tid] + scp_red[3][tid];
      atomicAdd(&SCP[bLn + l0 + tid], v * pm_s[tid]);
    }
  }
#pragma unroll
  for (int rt = 0; rt < 2; ++rt)
#pragma unroll
    for (int r4 = 0; r4 < 4; ++r4) {
      float s = sca_r[rt][r4];
      s += __shfl_xor(s, 1, 64); s += __shfl_xor(s, 2, 64);
      s += __shfl_xor(s, 4, 64); s += __shfl_xor(s, 8, 64);
      if ((lane & 15) == 0) {
        int nr = wv * 32 + rt * 16 + ((lane >> 4) << 2) + r4;
        atomicAdd(&SCA[(long)b * Nn + n0 + nr], s * am_sh[nr]);
      }
    }
}

// ---------------------------------------------------------------------------
// Legacy fp32 tiled matmul (head layers, K=386)
// ---------------------------------------------------------------------------
__global__ __launch_bounds__(256) void mm_kernel(
    const float* __restrict__ A, const float* __restrict__ Bm,
    const float* __restrict__ bias, float* __restrict__ C,
    int M, int N, int K, int lda, int ldb, int ldc, int colOff, int act)
{
  __shared__ float As[32][33];
  __shared__ float Bs[32][33];
  int tx = threadIdx.x, ty = threadIdx.y;
  int tid = ty * 16 + tx;
  int m0 = blockIdx.y * 32;
  int n0 = blockIdx.x * 32;
  float acc00 = 0.f, acc01 = 0.f, acc10 = 0.f, acc11 = 0.f;
  for (int k0 = 0; k0 < K; k0 += 32) {
#pragma unroll
    for (int t = 0; t < 4; ++t) {
      int li = tid + t * 256;
      int r = li >> 5, c = li & 31;
      int mm = m0 + r, kk = k0 + c;
      As[r][c] = (mm < M && kk < K) ? A[(long)mm * lda + kk] : 0.f;
      int kk2 = k0 + r, nn = n0 + c;
      Bs[r][c] = (kk2 < K && nn < N) ? Bm[(long)kk2 * ldb + nn] : 0.f;
    }
    __syncthreads();
#pragma unroll
    for (int kk = 0; kk < 32; ++kk) {
      float a0 = As[ty][kk], a1 = As[ty + 16][kk];
      float b0 = Bs[kk][tx], b1 = Bs[kk][tx + 16];
      acc00 += a0 * b0; acc01 += a0 * b1;
      acc10 += a1 * b0; acc11 += a1 * b1;
    }
    __syncthreads();
  }
  float accs[2][2] = {{acc00, acc01}, {acc10, acc11}};
#pragma unroll
  for (int i = 0; i < 2; ++i) {
    int m = m0 + ty + i * 16;
    if (m >= M) continue;
#pragma unroll
    for (int j = 0; j < 2; ++j) {
      int n = n0 + tx + j * 16;
      if (n >= N) continue;
      float v = accs[i][j];
      if (bias) v += bias[n];
      C[(long)m * ldc + colOff + n] = apply_act(v, act);
    }
  }
}

static void mm(hipStream_t st, const float* A, const float* Bm, const float* bias,
               float* C, int M, int N, int K, int lda, int ldb, int ldc,
               int colOff, int act)
{
  dim3 grid((N + 31) / 32, (M + 31) / 32), block(16, 16);
  mm_kernel<<<grid, block, 0, st>>>(A, Bm, bias, C, M, N, K, lda, ldb, ldc, colOff, act);
}

// ---------------------------------------------------------------------------
// GAT v3 (r9-validated): bitmask adj + register softmax stats + MFMA att@Wh.
// WhT: [b][n][k=256] bf16 (pre-transposed).  grid (Nn/32, Bn, heads).
// ---------------------------------------------------------------------------
template<int F>
__global__ __launch_bounds__(256) void gat3_kernel(
    const u16* __restrict__ WhT, long bStride,
    const float* __restrict__ f1, const float* __restrict__ f2,
    const u64* __restrict__ adjb,
    float* __restrict__ out, int ldo)
{
  __shared__ u16 sP[32 * 256];       // 16 KB, lofs<256>
  __shared__ u16 sW[F * 32];         // 4/8 KB, XOR (n&7)<<4
  __shared__ float f2s[256];
  __shared__ float f1s[32], mrow[32], srow[32];
  __shared__ u64 adjm[32][4];
  int b = blockIdx.y, i0 = blockIdx.x * 32, h = blockIdx.z;
  int tid = threadIdx.x, lane = tid & 63, wv = tid >> 6;
  const long rowb = (long)b * Nn;
  const float* f1h = f1 + (long)h * Bn * Nn;
  const float* f2h = f2 + (long)h * Bn * Nn;

  if (tid < 32) f1s[tid] = f1h[rowb + i0 + tid];
  f2s[tid] = f2h[rowb + tid];
  if (tid < 128) adjm[tid >> 2][tid & 3] = adjb[(rowb + i0 + (tid >> 2)) * 4 + (tid & 3)];
  __syncthreads();

  // phase A: per-row max + sum (8 lanes/row, e recomputed)
  {
    int r = tid >> 3, s = tid & 7;
    float f1v = f1s[r];
    float mx = -3.4e38f;
    for (int j = s; j < 256; j += 8) {
      bool bit = (adjm[r][j >> 6] >> (j & 63)) & 1;
      float e = f1v + f2s[j]; e = e > 0.f ? e : 0.2f * e;
      mx = fmaxf(mx, bit ? e : -9e15f);
    }
    mx = fmaxf(mx, __shfl_xor(mx, 1, 64));
    mx = fmaxf(mx, __shfl_xor(mx, 2, 64));
    mx = fmaxf(mx, __shfl_xor(mx, 4, 64));
    float sum = 0.f;
    for (int j = s; j < 256; j += 8) {
      bool bit = (adjm[r][j >> 6] >> (j & 63)) & 1;
      float e = f1v + f2s[j]; e = e > 0.f ? e : 0.2f * e;
      sum += __expf((bit ? e : -9e15f) - mx);
    }
    sum += __shfl_xor(sum, 1, 64);
    sum += __shfl_xor(sum, 2, 64);
    sum += __shfl_xor(sum, 4, 64);
    if (s == 0) { mrow[r] = mx; srow[r] = 1.f / sum; }
  }
  __syncthreads();
  // phase B: P (unnormalized, bf16) into sP
  {
    int j = tid;
    float f2v = f2s[j];
    int w64 = j >> 6, sh = j & 63;
    for (int r = 0; r < 32; ++r) {
      bool bit = (adjm[r][w64] >> sh) & 1;
      float e = f1s[r] + f2v; e = e > 0.f ? e : 0.2f * e;
      float p = __expf((bit ? e : -9e15f) - mrow[r]);
      *(u16*)((char*)sP + lofs<256>(r, j)) = bfc(p);
    }
  }
  // phase C: MFMA (32 x F) = sP(32x256) @ WhT^T
  constexpr int NT = F / 32;
  f32x4 acc[NT];
#pragma unroll
  for (int t = 0; t < NT; ++t) acc[t] = f32x4{0.f,0.f,0.f,0.f};
  const u16* Wb = WhT + (long)b * bStride + (long)h * F * 256;
  int mh = wv & 1;
  for (int k0 = 0; k0 < 256; k0 += 32) {
    __syncthreads();
    for (int q = tid; q < F * 4; q += 256) {
      int n = q >> 2, c8 = (q & 3) << 3;
      *(u32x4*)((char*)sW + ((n * 64 + c8 * 2) ^ ((n & 7) << 4))) =
          *(const u32x4*)(Wb + (long)n * 256 + k0 + c8);
    }
    __syncthreads();
    int kf = (lane >> 4) << 3;
    short8v a = ldsv(sP, lofs<256>(mh * 16 + (lane & 15), k0 + kf));
#pragma unroll
    for (int t = 0; t < NT; ++t) {
      int n = ((wv >> 1) * NT + t) * 16 + (lane & 15);
      short8v bb = *(const short8v*)((char*)sW + ((n * 64 + kf * 2) ^ ((n & 7) << 4)));
      acc[t] = MFMA(a, bb, acc[t]);
    }
  }
#pragma unroll
  for (int t = 0; t < NT; ++t) {
    int col = ((wv >> 1) * NT + t) * 16 + (lane & 15);
#pragma unroll
    for (int r4 = 0; r4 < 4; ++r4) {
      int rl = mh * 16 + ((lane >> 4) << 2) + r4;
      float v = acc[t][r4] * srow[rl];
      v = v > 0.f ? v : expm1f(v);   // elu
      out[(rowb + i0 + rl) * (long)ldo + h * F + col] = v;
    }
  }
}

// ---------------------------------------------------------------------------
// 11x11 conv (validated r3).  conv11e fuses the amino embedding (layer 1).
// ---------------------------------------------------------------------------
__global__ __launch_bounds__(128) void conv11_kernel(
    const float* __restrict__ in, const float* __restrict__ kw,
    const float* __restrict__ bias_p, float* __restrict__ out)
{
  __shared__ float s[26][140];
  __shared__ float kk[121];
  int b = blockIdx.y;
  int l0 = blockIdx.x * 16;
  int tid = threadIdx.x;
  if (tid < 121) kk[tid] = kw[tid];
  const float* inb = in + (long)b * Ln * PROT;
  for (int r = 0; r < 26; ++r) {
    int l = l0 - 5 + r;
    for (int c = tid; c < 138; c += 128) {
      int p = c - 5;
      float v = 0.f;
      if (l >= 0 && l < Ln && p >= 0 && p < PROT) v = inb[(long)l * PROT + p];
      s[r][c] = v;
    }
  }
  __syncthreads();
  float bias = bias_p[0];
  float acc[16];
#pragma unroll
  for (int i = 0; i < 16; ++i) acc[i] = bias;
  int p = tid;
#pragma unroll
  for (int v = 0; v < 11; ++v) {
    float c[26];
#pragma unroll
    for (int u = 0; u < 26; ++u) c[u] = s[u][p + v];
#pragma unroll
    for (int u = 0; u < 11; ++u) {
      float w = kk[u * 11 + v];
#pragma unroll
      for (int i = 0; i < 16; ++i) acc[i] += c[i + u] * w;
    }
  }
  float* outb = out + (long)b * Ln * PROT;
#pragma unroll
  for (int i = 0; i < 16; ++i) {
    float vv = acc[i];
    outb[(long)(l0 + i) * PROT + p] = vv > 0.f ? vv : 0.2f * vv;
  }
}

__global__ __launch_bounds__(128) void conv11e_kernel(
    const int* __restrict__ amino, const float* __restrict__ E,
    const float* __restrict__ kw, const float* __restrict__ bias_p,
    float* __restrict__ out)
{
  __shared__ float s[26][140];
  __shared__ float kk[121];
  int b = blockIdx.y;
  int l0 = blockIdx.x * 16;
  int tid = threadIdx.x;
  if (tid < 121) kk[tid] = kw[tid];
  const int* amb = amino + (long)b * Ln;
  for (int r = 0; r < 26; ++r) {
    int l = l0 - 5 + r;
    int idx = (l >= 0 && l < Ln) ? amb[l] : -1;
    const float* Er = E + (long)(idx < 0 ? 0 : idx) * PROT;
    for (int c = tid; c < 138; c += 128) {
      int p = c - 5;
      float v = 0.f;
      if (idx >= 0 && p >= 0 && p < PROT) v = Er[p];
      s[r][c] = v;
    }
  }
  __syncthreads();
  float bias = bias_p[0];
  float acc[16];
#pragma unroll
  for (int i = 0; i < 16; ++i) acc[i] = bias;
  int p = tid;
#pragma unroll
  for (int v = 0; v < 11; ++v) {
    float c[26];
#pragma unroll
    for (int u = 0; u < 26; ++u) c[u] = s[u][p + v];
#pragma unroll
    for (int u = 0; u < 11; ++u) {
      float w = kk[u * 11 + v];
#pragma unroll
      for (int i = 0; i < 16; ++i) acc[i] += c[i + u] * w;
    }
  }
  float* outb = out + (long)b * Ln * PROT;
#pragma unroll
  for (int i = 0; i < 16; ++i) {
    float vv = acc[i];
    outb[(long)(l0 + i) * PROT + p] = vv > 0.f ? vv : 0.2f * vv;
  }
}

// ---------------------------------------------------------------------------
// masked softmax (grid.y = iteration)
// ---------------------------------------------------------------------------
__global__ __launch_bounds__(256) void mask_softmax_kernel(
    const float* __restrict__ score, const float* __restrict__ mask,
    float* __restrict__ att, int n)
{
  int b = blockIdx.x;
  long st = (long)blockIdx.y * gridDim.x * n;
  int tid = threadIdx.x;
  __shared__ float red[256];
  const float* s = score + st + (long)b * n;
  const float* mk = mask + (long)b * n;
  float mx = -3.4e38f;
  for (int i = tid; i < n; i += 256) mx = fmaxf(mx, s[i]);
  red[tid] = mx; __syncthreads();
  for (int stp = 128; stp > 0; stp >>= 1) { if (tid < stp) red[tid] = fmaxf(red[tid], red[tid + stp]); __syncthreads(); }
  mx = red[0]; __syncthreads();
  float sum = 0.f;
  for (int i = tid; i < n; i += 256) sum += __expf(s[i] - mx) * mk[i];
  red[tid] = sum; __syncthreads();
  for (int stp = 128; stp > 0; stp >>= 1) { if (tid < stp) red[tid] += red[tid + stp]; __syncthreads(); }
  float denom = red[0] + 1e-6f;
  for (int i = tid; i < n; i += 256)
    att[st + (long)b * n + i] = __expf(s[i] - mx) * mk[i] / denom;
}

// ---------------------------------------------------------------------------
// weighted sum: all 4 iterations per pass (x read once). grid (Bn, nsplit).
// att layout [it][Bn][n]; out[b][it*128 + d].  Out pre-zeroed.
// ---------------------------------------------------------------------------
template<int XBF>
__global__ __launch_bounds__(128) void wsum_kernel(
    const void* __restrict__ xp, const float* __restrict__ att,
    float* __restrict__ out, int n, int nsplit)
{
  int b = blockIdx.x;
  int sp = blockIdx.y;
  int d = threadIdx.x;
  int chunk = n / nsplit;
  int t0 = sp * chunk, t1 = t0 + chunk;
  long bn = (long)b * n;
  long itS = (long)Bn * n;
  float acc[4] = {0.f, 0.f, 0.f, 0.f};
  if (XBF) {
    const u16* xb = (const u16*)xp + bn * LT + d;
    for (int t = t0; t < t1; ++t) {
      float xv = bf2f(xb[(long)t * LT]);
#pragma unroll
      for (int it = 0; it < 4; ++it) acc[it] += xv * att[it * itS + bn + t];
    }
  } else {
    const float* xb = (const float*)xp + bn * LT + d;
    for (int t = t0; t < t1; ++t) {
      float xv = xb[(long)t * LT];
#pragma unroll
      for (int it = 0; it < 4; ++it) acc[it] += xv * att[it * itS + bn + t];
    }
  }
#pragma unroll
  for (int it = 0; it < 4; ++it)
    atomicAdd(&out[(long)b * 512 + it * LT + d], acc[it]);
}

__global__ __launch_bounds__(128) void assemble_v_kernel(
    const float* __restrict__ sf, const float* __restrict__ invT,
    const float* __restrict__ T, float* __restrict__ v)
{
  int b = blockIdx.x;
  int t = threadIdx.x;
  v[(long)b * DOUT + 128 + t] = sf[(long)b * LT + t];
  if (t == 0) { v[(long)b * DOUT + 384] = invT[b]; v[(long)b * DOUT + 385] = T[b]; }
}

// ---------------------------------------------------------------------------
extern "C" void kernel_launch(void* const* d_in, const int* in_sizes, int n_in,
                              void* d_out, int out_size, void* d_ws, size_t ws_size,
                              hipStream_t stream) {
  const long NB = (long)Bn * Nn;    // 16384
  const long LB = (long)Bn * Ln;    // 131072
  const long M1 = 1024 * 1024;

  const int*   atoms      = (const int*)d_in[0];
  const float* atoms_mask = (const float*)d_in[1];
  const int*   adj        = (const int*)d_in[2];
  const int*   amino      = (const int*)d_in[3];
  const float* amino_mask = (const float*)d_in[4];
  const float* fps        = (const float*)d_in[5];
  const float* invT       = (const float*)d_in[6];
  const float* Temp       = (const float*)d_in[7];
  const float* E_atom     = (const float*)d_in[8];
  const float* E_amino    = (const float*)d_in[9];
  const float* gatW       = (const float*)d_in[10];
  const float* gatA       = (const float*)d_in[11];
  const float* goW        = (const float*)d_in[12];
  const float* goA        = (const float*)d_in[13];
  const float* Wc_w       = (const float*)d_in[14];
  const float* Wc_b       = (const float*)d_in[15];
  const float* conv_k     = (const float*)d_in[16];
  const float* conv_b     = (const float*)d_in[17];
  const float* Wp_w       = (const float*)d_in[18];
  const float* Wp_b       = (const float*)d_in[19];
  const float* fp0        = (const float*)d_in[20];
  const float* fp1        = (const float*)d_in[21];
  const float* U          = (const float*)d_in[22];
  const float* t_c2p_w    = (const float*)d_in[23];
  const float* t_c2p_b    = (const float*)d_in[24];
  const float* t_p2c_w    = (const float*)d_in[25];
  const float* t_p2c_b    = (const float*)d_in[26];
  const float* bh_c_w     = (const float*)d_in[27];
  const float* bh_c_b     = (const float*)d_in[28];
  const float* bh_p_w     = (const float*)d_in[29];
  const float* bh_p_b     = (const float*)d_in[30];
  const float* ba_c_w     = (const float*)d_in[31];
  const float* ba_c_b     = (const float*)d_in[32];
  const float* ba_p_w     = (const float*)d_in[33];
  const float* ba_p_b     = (const float*)d_in[34];
  const float* comb_c_w   = (const float*)d_in[35];
  const float* comb_c_b   = (const float*)d_in[36];
  const float* comb_p_w   = (const float*)d_in[37];
  const float* comb_p_b   = (const float*)d_in[38];
  const float* Wout_w     = (const float*)d_in[39];
  const float* Wout_b     = (const float*)d_in[40];
  const float* out_w      = (const float*)d_in[41];
  const float* out_b      = (const float*)d_in[42];
  float* out = (float*)d_out;

  // ---------------- workspace layout (~98 MB) ----------------
  float* ws = (float*)d_ws;
  long off = 0;
  float* AV    = ws + off; off += NB * LT;          // 2M fp32
  u16*   PVbf  = (u16*)(ws + off); off += LB * LT / 2;
  float* SF    = ws + off; off += (long)Bn * LT;
  float* SFT   = ws + off; off += (long)Bn * LT;
  float* CF    = ws + off; off += (long)Bn * 512;
  float* PF    = ws + off; off += (long)Bn * 512;
  float* F1    = ws + off; off += 4 * NB;
  float* F2    = ws + off; off += 4 * NB;
  float* ATTA4 = ws + off; off += 4 * NB;
  float* ATTP4 = ws + off; off += 4 * LB;
  float* V0    = ws + off; off += (long)Bn * DOUT;
  float* V1    = ws + off; off += (long)Bn * DOUT;
  u64*   ADJB  = (u64*)(ws + off); off += NB * 4 * 2;   // [NB][4] u64
  float* WVEC  = ws + off; off += 2048;                 // 1536 used
  // weight cache (persistent)
  u16* WT = (u16*)(ws + off);
  long wo = 0;
  u16* gatW_t  = WT + wo; wo += 4L * 64 * 128;      // [256 n][128 k]
  u16* goW_t   = WT + wo; wo += 128L * 256;
  u16* T23     = WT + wo; wo += 23L * 16384;
  u16* fp0_t   = WT + wo; wo += 128L * 1024;
  u16* combc_t = WT + wo; wo += 128L * 512;
  u16* combp_t = WT + wo; wo += 128L * 512;
  off += (wo + 1) / 2;
  float* pk_a = ws + off; off += 2056;
  float* pk_p = ws + off; off += 2056;
  float* POOL = ws + off;                           // needs 16.78M floats
  u16* Wc_t   = T23;
  u16* Wp_t   = T23 + 16384;
  u16* fp1_t  = T23 + 2L * 16384;
  u16* U_t    = T23 + 3L * 16384;                   // 4 mats contiguous
  u16* wcat_a = T23 + 7L * 16384;                   // [bh_c(4) | t_c2p(4)]
  u16* wcat_p = T23 + 15L * 16384;                  // [bh_p(4) | t_p2c(4)]
  // pool aliases:
  float* AVE   = POOL;                              // [0,2M)
  u16*   WhRM4 = (u16*)(POOL + 2 * M1);             // [NB][256] u16 = [2M,4M)
  u16*   WhT4  = (u16*)(POOL + 4 * M1);             // [b][256][256] u16 = [4M,6M)
  float* MH    = POOL + 6 * M1;                     // [6M,10.2M)
  u16*   WhRM2 = (u16*)POOL;                        // [NB][128] u16 = [0,1M)  (AVE dead)
  u16*   WhT2  = (u16*)(POOL + 1 * M1);             // [b][128][256] u16 = [1M,2M)
  float* G2    = POOL + 2 * M1;                     // [2M,4M)  (WhRM4 dead)
  float* PVA   = POOL;                              // CNN ping [0,8.39M)
  float* PVB   = POOL + 8 * M1;                     // CNN pong
  u16*   AVU4  = (u16*)POOL;                        // [NB][512] u16 = [0,4M)
  float* OUTP  = POOL + 4 * M1;                     // [8][LB]
  float* OUTA  = POOL + 5 * M1;                     // [8][NB]

  // ======================= weight prep =======================
  transp_kernel<<<dim3(32, 4), 256, 0, stream>>>(gatW, gatW_t, 128, 64);
  transp_kernel<<<dim3(128), 256, 0, stream>>>(goW, goW_t, 256, 128);
  transp_kernel<<<dim3(512), 256, 0, stream>>>(fp0, fp0_t, 1024, 128);
  transp_kernel<<<dim3(256), 256, 0, stream>>>(comb_c_w, combc_t, 512, 128);
  transp_kernel<<<dim3(256), 256, 0, stream>>>(comb_p_w, combp_t, 512, 128);
  {
    Ptr8 a1 = {{Wc_w, Wp_w, fp1, U, U + 16384, U + 32768, U + 49152, bh_c_w}};
    Ptr8 a2 = {{bh_c_w + 16384, bh_c_w + 32768, bh_c_w + 49152,
                t_c2p_w, t_c2p_w + 16384, t_c2p_w + 32768, t_c2p_w + 49152,
                bh_p_w}};
    Ptr8 a3 = {{bh_p_w + 16384, bh_p_w + 32768, bh_p_w + 49152,
                t_p2c_w, t_p2c_w + 16384, t_p2c_w + 32768, t_p2c_w + 49152,
                bh_p_w}};
    transp8_kernel<<<dim3(64, 8), 256, 0, stream>>>(a1, T23);
    transp8_kernel<<<dim3(64, 8), 256, 0, stream>>>(a2, T23 + 8L * 16384);
    transp8_kernel<<<dim3(64, 7), 256, 0, stream>>>(a3, T23 + 16L * 16384);
  }
  pack_kernel<<<dim3(9), 256, 0, stream>>>(bh_c_b, t_c2p_b, ba_c_w, ba_c_b,
                                           ba_p_w, bh_p_b, t_p2c_b, ba_p_b,
                                           pk_a, pk_p);
  packadj_kernel<<<dim3((unsigned)(NB * Nn / 256)), 256, 0, stream>>>(adj, ADJB);
  wvec_kernel<<<dim3(6), 256, 0, stream>>>(gatW, gatA, goW, goA, WVEC);

  // ======================= comp GAT (MFMA, bitmask) =======================
  embed_kernel<<<dim3((unsigned)((NB * CMP + 255) / 256)), 256, 0, stream>>>(
      atoms, E_atom, AVE, NB * CMP, CMP);
  // WhRM4 [NB][256] bf16 (coalesced), then LDS-tiled transpose -> WhT4
  mmx<0, 1>(stream, AVE, gatW_t, nullptr, WhRM4, (int)NB, 256, 128, 128, 256);
  transpT_kernel<<<dim3(4, 4, Bn), 256, 0, stream>>>(WhRM4, WhT4, 256);
  favv_kernel<<<dim3((unsigned)(NB / 4)), 256, 0, stream>>>(AVE, WVEC, F1, F2, NB);
  gat3_kernel<GF><<<dim3(Nn / 32, Bn, 4), 256, 0, stream>>>(
      WhT4, 256L * 256, F1, F2, ADJB, MH, 256);
  mmx<0, 1>(stream, MH, goW_t, nullptr, WhRM2, (int)NB, 128, 256, 256, 128);
  transpT_kernel<<<dim3(2, 4, Bn), 256, 0, stream>>>(WhRM2, WhT2, 128);
  fmh_kernel<<<dim3((unsigned)(NB / 4)), 256, 0, stream>>>(MH, WVEC + 1024, F1, F2, NB);
  gat3_kernel<CMP><<<dim3(Nn / 32, Bn, 1), 256, 0, stream>>>(
      WhT2, 128L * 256, F1, F2, ADJB, G2, 128);
  mmx<1, 0>(stream, G2, Wc_t, Wc_b, AV, (int)NB, 128, 128, 128, 128);

  // ======================= prot CNN (embed fused into conv1) ===============
  for (int c = 0; c < NCH; ++c) {
    long b0 = (long)c * CB;
    conv11e_kernel<<<dim3(Ln / 16, CB), 128, 0, stream>>>(
        amino + b0 * Ln, E_amino, conv_k + 0 * 121, conv_b + 0, PVA);
    conv11_kernel<<<dim3(Ln / 16, CB), 128, 0, stream>>>(PVA, conv_k + 1 * 121, conv_b + 1, PVB);
    conv11_kernel<<<dim3(Ln / 16, CB), 128, 0, stream>>>(PVB, conv_k + 2 * 121, conv_b + 2, PVA);
    mmx<1, 1>(stream, PVA, Wp_t, Wp_b, PVbf + b0 * Ln * 128,
              (int)((long)CB * Ln), 128, 128, 128, 128);
  }

  // ======================= fingerprint =======================
  mmx<2, 0>(stream, fps, fp0_t, nullptr, SFT, Bn, 128, 1024, 1024, 128);
  mmx<2, 0>(stream, SFT, fp1_t, nullptr, SF, Bn, 128, 128, 128, 128);

  // ======================= bidirectional attention =======================
  mmdot_kernel<1><<<dim3((unsigned)(LB / 128), 2), 256, 0, stream>>>(
      PVbf, wcat_p, pk_p, OUTP, LB);
  mmdot_kernel<0><<<dim3((unsigned)(NB / 128), 2), 256, 0, stream>>>(
      AV, wcat_a, pk_a, OUTA, NB);
  mmx<0, 1>(stream, AV, U_t, nullptr, AVU4, (int)NB, 512, 128, 128, 512);
  zero_kernel<<<dim3((unsigned)((2L * Bn * 512 + 255) / 256)), 256, 0, stream>>>(
      CF, 2L * Bn * 512);
  bidat_fused<<<dim3(Nn / 128, Bn, FLSP * 4), 256, 0, stream>>>(
      AVU4, PVbf, OUTP, OUTA, atoms_mask, amino_mask);
  mask_softmax_kernel<<<dim3(Bn, 4), 256, 0, stream>>>(OUTA, atoms_mask, ATTA4, Nn);
  mask_softmax_kernel<<<dim3(Bn, 4), 256, 0, stream>>>(OUTP, amino_mask, ATTP4, Ln);
  wsum_kernel<0><<<dim3(Bn, 4), 128, 0, stream>>>(AV, ATTA4, CF, Nn, 4);
  wsum_kernel<1><<<dim3(Bn, 16), 128, 0, stream>>>(PVbf, ATTP4, PF, Ln, 16);

  // ======================= head =======================
  mmx<0, 0>(stream, CF, combc_t, comb_c_b, V0, Bn, 128, 512, 512, DOUT, 0);
  mmx<0, 0>(stream, PF, combp_t, comb_p_b, V0, Bn, 128, 512, 512, DOUT, 256);
  assemble_v_kernel<<<Bn, 128, 0, stream>>>(SF, invT, Temp, V0);
  mm(stream, V0, Wout_w,                     Wout_b,            V1, Bn, DOUT, DOUT, DOUT, DOUT, DOUT, 0, 1);
  mm(stream, V1, Wout_w + (long)DOUT * DOUT, Wout_b + DOUT,     V0, Bn, DOUT, DOUT, DOUT, DOUT, DOUT, 0, 1);
  mm(stream, V0, Wout_w + 2L * DOUT * DOUT,  Wout_b + 2 * DOUT, V1, Bn, DOUT, DOUT, DOUT, DOUT, DOUT, 0, 1);
  mm(stream, V1, out_w, out_b, out, Bn, 1, DOUT, DOUT, 1, 1, 0, 0);
}

// Round 11
// 1105.722 us; speedup vs baseline: 1.1618x; 1.1618x over previous
//
#include <hip/hip_runtime.h>
#include <math.h>

// ---------------------------------------------------------------------------
// Model constants
// ---------------------------------------------------------------------------
#define Bn   64
#define Nn   256
#define Ln   2048
#define CMP  128
#define PROT 128
#define GF   64
#define NHEADS 4
#define LT   128
#define DOUT 386   // 3*LATENT + 2
#define CB   32    // batch chunk (CNN staging)
#define NCH  (Bn / CB)
#define FLSP 4     // bidat_fused l-split

typedef unsigned short u16;
typedef unsigned long long u64;
typedef __attribute__((ext_vector_type(8))) short short8v;   // 8 bf16 (4 VGPRs)
typedef __attribute__((ext_vector_type(4))) float f32x4;
typedef __attribute__((ext_vector_type(4))) unsigned short u16x4;
typedef __attribute__((ext_vector_type(4))) unsigned int u32x4;

#define MFMA(a, b, c) __builtin_amdgcn_mfma_f32_16x16x32_bf16((a), (b), (c), 0, 0, 0)

__device__ __forceinline__ float apply_act(float v, int act) {
  if (act == 1) return v > 0.f ? v : 0.2f * v;   // lrelu ALPHA
  if (act == 2) return v > 0.f ? v : 0.1f * v;   // lrelu 0.1 (fingerprint)
  if (act == 3) return tanhf(v);
  return v;
}

__device__ __forceinline__ u16 bfc(float f) {    // fp32 -> bf16 RNE
  union { float f; unsigned u; } x; x.f = f;
  unsigned r = x.u + 0x7fffu + ((x.u >> 16) & 1u);
  return (u16)(r >> 16);
}

__device__ __forceinline__ float bf2f(u16 h) {
  union { unsigned u; float f; } x; x.u = ((unsigned)h) << 16; return x.f;
}

// fast tanh: 1 - 2*rcp(2^(2*log2e*x)+1); HW exp2+rcp, ~1e-6 abs err, saturates
__device__ __forceinline__ float ftanh(float x) {
  float e = __builtin_amdgcn_exp2f(x * 2.885390081777927f);
  return 1.f - 2.f * __builtin_amdgcn_rcpf(e + 1.f);
}

// byte offset into a [R][C] bf16 LDS tile, XOR-swizzled (r7-validated: 0 conflicts)
template<int C>
__device__ __forceinline__ int lofs(int r, int c) {
  if (C == 256) return ((r * C + c) * 2) ^ ((r & 15) << 4);
  if (C == 128) return ((r * C + c) * 2) ^ ((r & 15) << 4);
  return ((r * C + c) * 2) ^ ((r & 7) << 4);
}

__device__ __forceinline__ short8v ldsv(const u16* s, int byteofs) {
  return *(const short8v*)((const char*)s + byteofs);
}

// ---------------------------------------------------------------------------
// Embedding gather (atoms only)
// ---------------------------------------------------------------------------
__global__ void embed_kernel(const int* __restrict__ idx, const float* __restrict__ E,
                             float* __restrict__ out, long total, int C) {
  long i = (long)blockIdx.x * blockDim.x + threadIdx.x;
  if (i >= total) return;
  long r = i / C;
  int c = (int)(i - r * (long)C);
  out[i] = E[(long)idx[r] * C + c];
}

__global__ void zero_kernel(float* __restrict__ a, long n) {
  long i = (long)blockIdx.x * blockDim.x + threadIdx.x;
  if (i < n) a[i] = 0.f;
}

// adjacency -> bitmask [NB rows][4 u64]
__global__ void packadj_kernel(const int* __restrict__ adj, u64* __restrict__ adjb) {
  long idx = (long)blockIdx.x * 256 + threadIdx.x;
  int lane = threadIdx.x & 63;
  bool bit = adj[idx] > 0;
  u64 m = __ballot(bit);
  if (lane == 0) adjb[idx >> 6] = m;
}

// ---------------------------------------------------------------------------
// Weight prep: dst[z][n*K + k] = bf16(src[z][k*N + n])
// ---------------------------------------------------------------------------
__global__ void transp_kernel(const float* __restrict__ src, u16* __restrict__ dst,
                              int K, int N) {
  long total = (long)K * N;
  long base = (long)blockIdx.y * total;
  long idx = (long)blockIdx.x * 256 + threadIdx.x;
  if (idx >= total) return;
  int k = (int)(idx % K);
  int n = (int)(idx / K);
  dst[base + idx] = bfc(src[base + (long)k * N + n]);
}

struct Ptr8 { const float* p[8]; };
__global__ void transp8_kernel(Ptr8 srcs, u16* __restrict__ dst) {
  int y = blockIdx.y;
  int idx = blockIdx.x * 256 + threadIdx.x;   // 0..16383
  int k = idx & 127, n = idx >> 7;
  dst[(long)y * 16384 + idx] = bfc(srcs.p[y][k * 128 + n]);
}

// wv[0,1024): gat head vectors w[h][which][128]; wv[1024,1536): go vectors [2][256]
__global__ void wvec_kernel(const float* __restrict__ gatW, const float* __restrict__ gatA,
                            const float* __restrict__ goW, const float* __restrict__ goA,
                            float* __restrict__ wv) {
  int idx = blockIdx.x * 256 + threadIdx.x;
  if (idx < 1024) {
    int h = idx >> 8, wq = (idx >> 7) & 1, d = idx & 127;
    const float* W = gatW + ((long)h * 128 + d) * 64;
    const float* a = gatA + h * 128 + wq * 64;
    float s = 0.f;
    for (int f = 0; f < 64; ++f) s += W[f] * a[f];
    wv[idx] = s;
  } else if (idx < 1536) {
    int k = idx - 1024; int wq = k >> 8, d = k & 255;
    const float* W = goW + (long)d * 128;
    const float* a = goA + wq * 128;
    float s = 0.f;
    for (int f = 0; f < 128; ++f) s += W[f] * a[f];
    wv[idx] = s;
  }
}

// f1/f2 for 4 heads from AVE: one wave per row
__global__ __launch_bounds__(256) void favv_kernel(
    const float* __restrict__ AVE, const float* __restrict__ wv,
    float* __restrict__ f1, float* __restrict__ f2, long rows)
{
  __shared__ float w[1024];
  int tid = threadIdx.x;
  for (int q = tid; q < 1024; q += 256) w[q] = wv[q];
  __syncthreads();
  long r = (long)blockIdx.x * 4 + (tid >> 6);
  int lane = tid & 63;
  float a0 = AVE[r * 128 + lane], a1 = AVE[r * 128 + 64 + lane];
#pragma unroll
  for (int h = 0; h < 4; ++h) {
    float s1 = a0 * w[h * 256 + lane] + a1 * w[h * 256 + 64 + lane];
    float s2 = a0 * w[h * 256 + 128 + lane] + a1 * w[h * 256 + 192 + lane];
#pragma unroll
    for (int m = 32; m; m >>= 1) { s1 += __shfl_xor(s1, m, 64); s2 += __shfl_xor(s2, m, 64); }
    if (lane == 0) { f1[(long)h * rows + r] = s1; f2[(long)h * rows + r] = s2; }
  }
}

// f1/f2 from MH [rows][256] with gv = wv+1024
__global__ __launch_bounds__(256) void fmh_kernel(
    const float* __restrict__ MH, const float* __restrict__ gv,
    float* __restrict__ f1, float* __restrict__ f2, long rows)
{
  __shared__ float w[512];
  int tid = threadIdx.x;
  for (int q = tid; q < 512; q += 256) w[q] = gv[q];
  __syncthreads();
  long r = (long)blockIdx.x * 4 + (tid >> 6);
  int lane = tid & 63;
  const float* m = MH + r * 256;
  float s1 = 0.f, s2 = 0.f;
#pragma unroll
  for (int t = 0; t < 4; ++t) {
    float a = m[t * 64 + lane];
    s1 += a * w[t * 64 + lane];
    s2 += a * w[256 + t * 64 + lane];
  }
#pragma unroll
  for (int mm = 32; mm; mm >>= 1) { s1 += __shfl_xor(s1, mm, 64); s2 += __shfl_xor(s2, mm, 64); }
  if (lane == 0) { f1[r] = s1; f2[r] = s2; }
}

// ---------------------------------------------------------------------------
// pack bvec/aw/ab for mmdot (r6-validated)
// ---------------------------------------------------------------------------
__global__ void pack_kernel(
    const float* __restrict__ bh_c_b, const float* __restrict__ t_c2p_b,
    const float* __restrict__ ba_c_w, const float* __restrict__ ba_c_b,
    const float* __restrict__ ba_p_w, const float* __restrict__ bh_p_b,
    const float* __restrict__ t_p2c_b, const float* __restrict__ ba_p_b,
    float* __restrict__ pk_a, float* __restrict__ pk_p)
{
  int idx = blockIdx.x * 256 + threadIdx.x;
  if (idx < 1024) {
    int g = idx >> 7, j = idx & 127;
    pk_a[idx] = g < 4 ? bh_c_b[g * 128 + j] : t_c2p_b[(g - 4) * 128 + j];
    pk_p[idx] = g < 4 ? bh_p_b[g * 128 + j] : t_p2c_b[(g - 4) * 128 + j];
  } else if (idx < 2048) {
    int k = idx - 1024; int g = k >> 7, j = k & 127;
    pk_a[idx] = g < 4 ? ba_c_w[g * 256 + j] : ba_p_w[(g - 4) * 256 + 128 + j];
    pk_p[idx] = g < 4 ? ba_p_w[g * 256 + j] : ba_c_w[(g - 4) * 256 + 128 + j];
  } else if (idx < 2056) {
    int g = idx - 2048;
    pk_a[idx] = g < 4 ? ba_c_b[g] : 0.f;
    pk_p[idx] = g < 4 ? ba_p_b[g] : 0.f;
  }
}

// ---------------------------------------------------------------------------
// MFMA GEMM: C = act(A @ B + bias).  A fp32 [M,K], Bt bf16 [N,K].
// OUT=0: fp32 C[row*ldc+colOff+col];  OUT=1: bf16 C[row*ldc+col]
// OUT=2: bf16 transposed-blocked C[(row/MBc)*BSt + col*ldt + (row%MBc)]
// ---------------------------------------------------------------------------
template<int ACT, int OUT>
__global__ __launch_bounds__(256) void mfma_mm_kernel(
    const float* __restrict__ A, const u16* __restrict__ Bt,
    const float* __restrict__ bias, void* __restrict__ Cp,
    int M, int N, int K, int lda, int ldc, int colOff,
    int MBc, long BSt, int ldt)
{
  __shared__ u16 sA[64 * 64];
  __shared__ u16 sB[64 * 64];
  int m0 = blockIdx.y * 64, n0 = blockIdx.x * 64;
  int tid = threadIdx.x, lane = tid & 63, wv = tid >> 6;
  int mh = wv >> 1, nh = wv & 1;
  f32x4 acc00 = {0.f,0.f,0.f,0.f};
  f32x4 acc01 = acc00, acc10 = acc00, acc11 = acc00;
  for (int k0 = 0; k0 < K; k0 += 64) {
#pragma unroll
    for (int q = tid; q < 64 * 16; q += 256) {
      int r = q >> 4, c4 = (q & 15) << 2;
      float4 v = *(const float4*)(A + (long)(m0 + r) * lda + k0 + c4);
      u16x4 h = { bfc(v.x), bfc(v.y), bfc(v.z), bfc(v.w) };
      *(u16x4*)((char*)sA + lofs<64>(r, c4)) = h;
    }
#pragma unroll
    for (int q = tid; q < 64 * 8; q += 256) {
      int r = q >> 3, c8 = (q & 7) << 3;
      *(u32x4*)((char*)sB + lofs<64>(r, c8)) =
          *(const u32x4*)(Bt + (long)(n0 + r) * K + k0 + c8);
    }
    __syncthreads();
#pragma unroll
    for (int kk = 0; kk < 64; kk += 32) {
      int kf = kk + ((lane >> 4) << 3);
      short8v a0 = ldsv(sA, lofs<64>(mh * 32 + (lane & 15), kf));
      short8v a1 = ldsv(sA, lofs<64>(mh * 32 + 16 + (lane & 15), kf));
      short8v b0 = ldsv(sB, lofs<64>(nh * 32 + (lane & 15), kf));
      short8v b1 = ldsv(sB, lofs<64>(nh * 32 + 16 + (lane & 15), kf));
      acc00 = MFMA(a0, b0, acc00);
      acc01 = MFMA(a0, b1, acc01);
      acc10 = MFMA(a1, b0, acc10);
      acc11 = MFMA(a1, b1, acc11);
    }
    __syncthreads();
  }
#pragma unroll
  for (int rt = 0; rt < 2; ++rt) {
#pragma unroll
    for (int ct = 0; ct < 2; ++ct) {
      f32x4 a = rt == 0 ? (ct == 0 ? acc00 : acc01) : (ct == 0 ? acc10 : acc11);
      int col = n0 + nh * 32 + ct * 16 + (lane & 15);
      float bv = bias ? bias[col] : 0.f;
#pragma unroll
      for (int r4 = 0; r4 < 4; ++r4) {
        int row = m0 + mh * 32 + rt * 16 + ((lane >> 4) << 2) + r4;
        float v = apply_act(a[r4] + bv, ACT);
        if (OUT == 0)
          ((float*)Cp)[(long)row * ldc + colOff + col] = v;
        else if (OUT == 1)
          ((u16*)Cp)[(long)row * ldc + col] = bfc(v);
        else
          ((u16*)Cp)[(long)(row / MBc) * BSt + (long)col * ldt + (row % MBc)] = bfc(v);
      }
    }
  }
}

template<int ACT, int OUT>
static void mmx(hipStream_t st, const float* A, const u16* Bt, const float* bias,
                void* C, int M, int N, int K, int lda, int ldc, int colOff = 0,
                int MBc = 1, long BSt = 0, int ldt = 0)
{
  dim3 grid(N / 64, M / 64);
  mfma_mm_kernel<ACT, OUT><<<grid, dim3(256), 0, st>>>(
      A, Bt, bias, C, M, N, K, lda, ldc, colOff, MBc, BSt, ldt);
}

// ---------------------------------------------------------------------------
// mmdot (r9-validated): out[g][row] = sum_col ftanh((X@W_g)+bv)*aw + ab
// ---------------------------------------------------------------------------
template<int XBF>
__global__ __launch_bounds__(256) void mmdot_kernel(
    const void* __restrict__ Xp, const u16* __restrict__ Wcat,
    const float* __restrict__ pk, float* __restrict__ out, long M)
{
  __shared__ u16 sX[128 * 128];    // 32 KB
  __shared__ u16 sW[64 * 128];     // 16 KB
  __shared__ float bv_s[64], aw_s[64];
  long m0 = (long)blockIdx.x * 128;
  int g0 = blockIdx.y * 4;
  int tid = threadIdx.x, lane = tid & 63, wv = tid >> 6;
  if (XBF) {
    const u16* X = (const u16*)Xp;
    for (int q = tid; q < 128 * 16; q += 256) {
      int r = q >> 4, c8 = (q & 15) << 3;
      *(u32x4*)((char*)sX + lofs<128>(r, c8)) =
          *(const u32x4*)(X + (m0 + r) * 128 + c8);
    }
  } else {
    const float* X = (const float*)Xp;
    for (int q = tid; q < 128 * 32; q += 256) {
      int r = q >> 5, c4 = (q & 31) << 2;
      float4 v = *(const float4*)(X + (m0 + r) * 128 + c4);
      u16x4 h = { bfc(v.x), bfc(v.y), bfc(v.z), bfc(v.w) };
      *(u16x4*)((char*)sX + lofs<128>(r, c4)) = h;
    }
  }
  for (int gi = 0; gi < 4; ++gi) {
    int g = g0 + gi;
    float p[2][4] = {{0.f,0.f,0.f,0.f},{0.f,0.f,0.f,0.f}};
    for (int hh = 0; hh < 2; ++hh) {
      __syncthreads();                 // sX ready / protect sW+bv reuse
      for (int q = tid; q < 64 * 16; q += 256) {
        int r = q >> 4, c8 = (q & 15) << 3;
        *(u32x4*)((char*)sW + lofs<128>(r, c8)) =
            *(const u32x4*)(Wcat + (long)g * 16384 + (long)(hh * 64 + r) * 128 + c8);
      }
      if (tid < 64) {
        bv_s[tid] = pk[g * 128 + hh * 64 + tid];
        aw_s[tid] = pk[1024 + g * 128 + hh * 64 + tid];
      }
      __syncthreads();
      for (int lt = 0; lt < 4; ++lt) {
        int col = lt * 16 + (lane & 15);
        float bv = bv_s[col], awv = aw_s[col];
#pragma unroll
        for (int rt = 0; rt < 2; ++rt) {
          f32x4 c = {0.f,0.f,0.f,0.f};
#pragma unroll
          for (int kk = 0; kk < 128; kk += 32) {
            int kf = kk + ((lane >> 4) << 3);
            short8v a = ldsv(sX, lofs<128>(wv * 32 + rt * 16 + (lane & 15), kf));
            short8v bb = ldsv(sW, lofs<128>(lt * 16 + (lane & 15), kf));
            c = MFMA(a, bb, c);
          }
#pragma unroll
          for (int r4 = 0; r4 < 4; ++r4)
            p[rt][r4] += ftanh(c[r4] + bv) * awv;
        }
      }
    }
    float ab = pk[2048 + g];
#pragma unroll
    for (int rt = 0; rt < 2; ++rt)
#pragma unroll
      for (int r4 = 0; r4 < 4; ++r4) {
        float s = p[rt][r4];
        s += __shfl_xor(s, 1, 64); s += __shfl_xor(s, 2, 64);
        s += __shfl_xor(s, 4, 64); s += __shfl_xor(s, 8, 64);
        if ((lane & 15) == 0) {
          long row = m0 + wv * 32 + rt * 16 + ((lane >> 4) << 2) + r4;
          out[(long)g * M + row] = s + ab;
        }
      }
  }
}

// ---------------------------------------------------------------------------
// bidat_fused v3 (r9-validated): A-frags in registers, bf16 PV, fast tanh.
// ---------------------------------------------------------------------------
__global__ __launch_bounds__(256) void bidat_fused(
    const u16* __restrict__ AVU4,    // [Bn*Nn][512] bf16 (4 iters concat)
    const u16* __restrict__ PVbf,    // [Bn][Ln][128] bf16
    float* __restrict__ OUTP,        // [8][Bn*Ln]: g<4 SCP, g>=4 q
    float* __restrict__ OUTA,        // [8][Bn*Nn]: g<4 SCA, g>=4 r
    const float* __restrict__ am, const float* __restrict__ pm)
{
  __shared__ u16 sK[128 * 128];      // 32 KB
  __shared__ float qm_s[128], pm_s[128], amr_s[128], am_sh[128];
  __shared__ float scp_red[4][128];
  const long NBt = (long)Bn * Nn, LBt = (long)Bn * Ln;
  int b = blockIdx.y;
  int n0 = blockIdx.x * 128;
  int zz = blockIdx.z;
  int it = zz & 3, lz = zz >> 2;
  const float* qv = OUTP + (long)(4 + it) * LBt;
  const float* rv = OUTA + (long)(4 + it) * NBt;
  float* SCA = OUTA + (long)it * NBt;
  float* SCP = OUTP + (long)it * LBt;
  int tid = threadIdx.x, lane = tid & 63, wv = tid >> 6;

  short8v af[2][4];
  {
    long rbase = (long)b * Nn + n0 + wv * 32 + (lane & 15);
    int cbase = it * 128 + ((lane >> 4) << 3);
#pragma unroll
    for (int rt = 0; rt < 2; ++rt)
#pragma unroll
      for (int k4 = 0; k4 < 4; ++k4)
        af[rt][k4] = *(const short8v*)(AVU4 + (rbase + rt * 16) * 512 + cbase + k4 * 32);
  }
  if (tid < 128) {
    float amv = am[(long)b * Nn + n0 + tid];
    am_sh[tid] = amv;
    amr_s[tid] = amv * rv[(long)b * Nn + n0 + tid];
  }
  float sca_r[2][4] = {{0.f,0.f,0.f,0.f},{0.f,0.f,0.f,0.f}};
  const u16* pvb = PVbf + (long)b * Ln * 128;
  int lbeg = lz * (Ln / FLSP);

  for (int l0 = lbeg; l0 < lbeg + Ln / FLSP; l0 += 128) {
    __syncthreads();
    for (int q = tid; q < 128 * 16; q += 256) {
      int r = q >> 4, c8 = (q & 15) << 3;
      *(u32x4*)((char*)sK + lofs<128>(r, c8)) =
          *(const u32x4*)(pvb + (long)(l0 + r) * 128 + c8);
    }
    if (tid < 128) {
      float pmv = pm[(long)b * Ln + l0 + tid];
      pm_s[tid] = pmv;
      qm_s[tid] = pmv * qv[(long)b * Ln + l0 + tid];
    }
    __syncthreads();
    for (int lt = 0; lt < 8; ++lt) {
      float sp = 0.f;
      float qmv = qm_s[lt * 16 + (lane & 15)];
#pragma unroll
      for (int rt = 0; rt < 2; ++rt) {
        f32x4 c = {0.f,0.f,0.f,0.f};
#pragma unroll
        for (int k4 = 0; k4 < 4; ++k4) {
          short8v bb = ldsv(sK, lofs<128>(lt * 16 + (lane & 15),
                                          k4 * 32 + ((lane >> 4) << 3)));
          c = MFMA(af[rt][k4], bb, c);
        }
#pragma unroll
        for (int r4 = 0; r4 < 4; ++r4) {
          int nr = wv * 32 + rt * 16 + ((lane >> 4) << 2) + r4;
          float t = ftanh(c[r4]);
          sca_r[rt][r4] += t * qmv;
          sp += t * amr_s[nr];
        }
      }
      sp += __shfl_xor(sp, 16, 64);
      sp += __shfl_xor(sp, 32, 64);
      if (lane < 16) scp_red[wv][lt * 16 + lane] = sp;
    }
    __syncthreads();
    if (tid < 128) {
      float v = scp_red[0][tid] + scp_red[1][tid] + scp_red[2][tid] + scp_red[3][tid];
      atomicAdd(&SCP[(long)b * Ln + l0 + tid], v * pm_s[tid]);
    }
  }
#pragma unroll
  for (int rt = 0; rt < 2; ++rt)
#pragma unroll
    for (int r4 = 0; r4 < 4; ++r4) {
      float s = sca_r[rt][r4];
      s += __shfl_xor(s, 1, 64); s += __shfl_xor(s, 2, 64);
      s += __shfl_xor(s, 4, 64); s += __shfl_xor(s, 8, 64);
      if ((lane & 15) == 0) {
        int nr = wv * 32 + rt * 16 + ((lane >> 4) << 2) + r4;
        atomicAdd(&SCA[(long)b * Nn + n0 + nr], s * am_sh[nr]);
      }
    }
}

// ---------------------------------------------------------------------------
// Legacy fp32 tiled matmul (head layers, K=386)
// ---------------------------------------------------------------------------
__global__ __launch_bounds__(256) void mm_kernel(
    const float* __restrict__ A, const float* __restrict__ Bm,
    const float* __restrict__ bias, float* __restrict__ C,
    int M, int N, int K, int lda, int ldb, int ldc, int colOff, int act)
{
  __shared__ float As[32][33];
  __shared__ float Bs[32][33];
  int tx = threadIdx.x, ty = threadIdx.y;
  int tid = ty * 16 + tx;
  int m0 = blockIdx.y * 32;
  int n0 = blockIdx.x * 32;
  float acc00 = 0.f, acc01 = 0.f, acc10 = 0.f, acc11 = 0.f;
  for (int k0 = 0; k0 < K; k0 += 32) {
#pragma unroll
    for (int t = 0; t < 4; ++t) {
      int li = tid + t * 256;
      int r = li >> 5, c = li & 31;
      int mm = m0 + r, kk = k0 + c;
      As[r][c] = (mm < M && kk < K) ? A[(long)mm * lda + kk] : 0.f;
      int kk2 = k0 + r, nn = n0 + c;
      Bs[r][c] = (kk2 < K && nn < N) ? Bm[(long)kk2 * ldb + nn] : 0.f;
    }
    __syncthreads();
#pragma unroll
    for (int kk = 0; kk < 32; ++kk) {
      float a0 = As[ty][kk], a1 = As[ty + 16][kk];
      float b0 = Bs[kk][tx], b1 = Bs[kk][tx + 16];
      acc00 += a0 * b0; acc01 += a0 * b1;
      acc10 += a1 * b0; acc11 += a1 * b1;
    }
    __syncthreads();
  }
  float accs[2][2] = {{acc00, acc01}, {acc10, acc11}};
#pragma unroll
  for (int i = 0; i < 2; ++i) {
    int m = m0 + ty + i * 16;
    if (m >= M) continue;
#pragma unroll
    for (int j = 0; j < 2; ++j) {
      int n = n0 + tx + j * 16;
      if (n >= N) continue;
      float v = accs[i][j];
      if (bias) v += bias[n];
      C[(long)m * ldc + colOff + n] = apply_act(v, act);
    }
  }
}

static void mm(hipStream_t st, const float* A, const float* Bm, const float* bias,
               float* C, int M, int N, int K, int lda, int ldb, int ldc,
               int colOff, int act)
{
  dim3 grid((N + 31) / 32, (M + 31) / 32), block(16, 16);
  mm_kernel<<<grid, block, 0, st>>>(A, Bm, bias, C, M, N, K, lda, ldb, ldc, colOff, act);
}

// ---------------------------------------------------------------------------
// GAT v3 (r9-validated): bitmask adj + register softmax stats + MFMA att@Wh.
// ---------------------------------------------------------------------------
template<int F>
__global__ __launch_bounds__(256) void gat3_kernel(
    const u16* __restrict__ WhT, long bStride,
    const float* __restrict__ f1, const float* __restrict__ f2,
    const u64* __restrict__ adjb,
    float* __restrict__ out, int ldo)
{
  __shared__ u16 sP[32 * 256];       // 16 KB, lofs<256>
  __shared__ u16 sW[F * 32];         // 4/8 KB, XOR (n&7)<<4
  __shared__ float f2s[256];
  __shared__ float f1s[32], mrow[32], srow[32];
  __shared__ u64 adjm[32][4];
  int b = blockIdx.y, i0 = blockIdx.x * 32, h = blockIdx.z;
  int tid = threadIdx.x, lane = tid & 63, wv = tid >> 6;
  const long rowb = (long)b * Nn;
  const float* f1h = f1 + (long)h * Bn * Nn;
  const float* f2h = f2 + (long)h * Bn * Nn;

  if (tid < 32) f1s[tid] = f1h[rowb + i0 + tid];
  f2s[tid] = f2h[rowb + tid];
  if (tid < 128) adjm[tid >> 2][tid & 3] = adjb[(rowb + i0 + (tid >> 2)) * 4 + (tid & 3)];
  __syncthreads();

  {
    int r = tid >> 3, s = tid & 7;
    float f1v = f1s[r];
    float mx = -3.4e38f;
    for (int j = s; j < 256; j += 8) {
      bool bit = (adjm[r][j >> 6] >> (j & 63)) & 1;
      float e = f1v + f2s[j]; e = e > 0.f ? e : 0.2f * e;
      mx = fmaxf(mx, bit ? e : -9e15f);
    }
    mx = fmaxf(mx, __shfl_xor(mx, 1, 64));
    mx = fmaxf(mx, __shfl_xor(mx, 2, 64));
    mx = fmaxf(mx, __shfl_xor(mx, 4, 64));
    float sum = 0.f;
    for (int j = s; j < 256; j += 8) {
      bool bit = (adjm[r][j >> 6] >> (j & 63)) & 1;
      float e = f1v + f2s[j]; e = e > 0.f ? e : 0.2f * e;
      sum += __expf((bit ? e : -9e15f) - mx);
    }
    sum += __shfl_xor(sum, 1, 64);
    sum += __shfl_xor(sum, 2, 64);
    sum += __shfl_xor(sum, 4, 64);
    if (s == 0) { mrow[r] = mx; srow[r] = 1.f / sum; }
  }
  __syncthreads();
  {
    int j = tid;
    float f2v = f2s[j];
    int w64 = j >> 6, sh = j & 63;
    for (int r = 0; r < 32; ++r) {
      bool bit = (adjm[r][w64] >> sh) & 1;
      float e = f1s[r] + f2v; e = e > 0.f ? e : 0.2f * e;
      float p = __expf((bit ? e : -9e15f) - mrow[r]);
      *(u16*)((char*)sP + lofs<256>(r, j)) = bfc(p);
    }
  }
  constexpr int NT = F / 32;
  f32x4 acc[NT];
#pragma unroll
  for (int t = 0; t < NT; ++t) acc[t] = f32x4{0.f,0.f,0.f,0.f};
  const u16* Wb = WhT + (long)b * bStride + (long)h * F * 256;
  int mh = wv & 1;
  for (int k0 = 0; k0 < 256; k0 += 32) {
    __syncthreads();
    for (int q = tid; q < F * 4; q += 256) {
      int n = q >> 2, c8 = (q & 3) << 3;
      *(u32x4*)((char*)sW + ((n * 64 + c8 * 2) ^ ((n & 7) << 4))) =
          *(const u32x4*)(Wb + (long)n * 256 + k0 + c8);
    }
    __syncthreads();
    int kf = (lane >> 4) << 3;
    short8v a = ldsv(sP, lofs<256>(mh * 16 + (lane & 15), k0 + kf));
#pragma unroll
    for (int t = 0; t < NT; ++t) {
      int n = ((wv >> 1) * NT + t) * 16 + (lane & 15);
      short8v bb = *(const short8v*)((char*)sW + ((n * 64 + kf * 2) ^ ((n & 7) << 4)));
      acc[t] = MFMA(a, bb, acc[t]);
    }
  }
#pragma unroll
  for (int t = 0; t < NT; ++t) {
    int col = ((wv >> 1) * NT + t) * 16 + (lane & 15);
#pragma unroll
    for (int r4 = 0; r4 < 4; ++r4) {
      int rl = mh * 16 + ((lane >> 4) << 2) + r4;
      float v = acc[t][r4] * srow[rl];
      v = v > 0.f ? v : expm1f(v);   // elu
      out[(rowb + i0 + rl) * (long)ldo + h * F + col] = v;
    }
  }
}

// ---------------------------------------------------------------------------
// 11x11 conv v2: 256 threads, 32-row l-tile.  Same per-output FMA order as r3
// (bit-identical results); staging halves, occupancy ~2x.
// ---------------------------------------------------------------------------
__global__ __launch_bounds__(256) void conv11_kernel(
    const float* __restrict__ in, const float* __restrict__ kw,
    const float* __restrict__ bias_p, float* __restrict__ out)
{
  __shared__ float s[42][140];
  __shared__ float kk[121];
  int b = blockIdx.y;
  int l0 = blockIdx.x * 32;
  int tid = threadIdx.x;
  if (tid < 121) kk[tid] = kw[tid];
  const float* inb = in + (long)b * Ln * PROT;
  for (int li = tid; li < 42 * 138; li += 256) {
    int r = li / 138, c = li - r * 138;
    int l = l0 - 5 + r, p = c - 5;
    float v = 0.f;
    if (l >= 0 && l < Ln && p >= 0 && p < PROT) v = inb[(long)l * PROT + p];
    s[r][c] = v;
  }
  __syncthreads();
  float bias = bias_p[0];
  int p = tid & 127, hf = tid >> 7;
  int rb = hf * 16;
  float acc[16];
#pragma unroll
  for (int i = 0; i < 16; ++i) acc[i] = bias;
#pragma unroll
  for (int v = 0; v < 11; ++v) {
    float c[26];
#pragma unroll
    for (int u = 0; u < 26; ++u) c[u] = s[rb + u][p + v];
#pragma unroll
    for (int u = 0; u < 11; ++u) {
      float w = kk[u * 11 + v];
#pragma unroll
      for (int i = 0; i < 16; ++i) acc[i] += c[i + u] * w;
    }
  }
  float* outb = out + (long)b * Ln * PROT;
#pragma unroll
  for (int i = 0; i < 16; ++i) {
    float vv = acc[i];
    outb[(long)(l0 + rb + i) * PROT + p] = vv > 0.f ? vv : 0.2f * vv;
  }
}

__global__ __launch_bounds__(256) void conv11e_kernel(
    const int* __restrict__ amino, const float* __restrict__ E,
    const float* __restrict__ kw, const float* __restrict__ bias_p,
    float* __restrict__ out)
{
  __shared__ float s[42][140];
  __shared__ float kk[121];
  __shared__ int idxs[42];
  int b = blockIdx.y;
  int l0 = blockIdx.x * 32;
  int tid = threadIdx.x;
  if (tid < 121) kk[tid] = kw[tid];
  const int* amb = amino + (long)b * Ln;
  if (tid < 42) {
    int l = l0 - 5 + tid;
    idxs[tid] = (l >= 0 && l < Ln) ? amb[l] : -1;
  }
  __syncthreads();
  for (int li = tid; li < 42 * 138; li += 256) {
    int r = li / 138, c = li - r * 138;
    int p = c - 5;
    int idx = idxs[r];
    float v = 0.f;
    if (idx >= 0 && p >= 0 && p < PROT) v = E[(long)idx * PROT + p];
    s[r][c] = v;
  }
  __syncthreads();
  float bias = bias_p[0];
  int p = tid & 127, hf = tid >> 7;
  int rb = hf * 16;
  float acc[16];
#pragma unroll
  for (int i = 0; i < 16; ++i) acc[i] = bias;
#pragma unroll
  for (int v = 0; v < 11; ++v) {
    float c[26];
#pragma unroll
    for (int u = 0; u < 26; ++u) c[u] = s[rb + u][p + v];
#pragma unroll
    for (int u = 0; u < 11; ++u) {
      float w = kk[u * 11 + v];
#pragma unroll
      for (int i = 0; i < 16; ++i) acc[i] += c[i + u] * w;
    }
  }
  float* outb = out + (long)b * Ln * PROT;
#pragma unroll
  for (int i = 0; i < 16; ++i) {
    float vv = acc[i];
    outb[(long)(l0 + rb + i) * PROT + p] = vv > 0.f ? vv : 0.2f * vv;
  }
}

// ---------------------------------------------------------------------------
// masked softmax (grid.y = iteration)
// ---------------------------------------------------------------------------
__global__ __launch_bounds__(256) void mask_softmax_kernel(
    const float* __restrict__ score, const float* __restrict__ mask,
    float* __restrict__ att, int n)
{
  int b = blockIdx.x;
  long st = (long)blockIdx.y * gridDim.x * n;
  int tid = threadIdx.x;
  __shared__ float red[256];
  const float* s = score + st + (long)b * n;
  const float* mk = mask + (long)b * n;
  float mx = -3.4e38f;
  for (int i = tid; i < n; i += 256) mx = fmaxf(mx, s[i]);
  red[tid] = mx; __syncthreads();
  for (int stp = 128; stp > 0; stp >>= 1) { if (tid < stp) red[tid] = fmaxf(red[tid], red[tid + stp]); __syncthreads(); }
  mx = red[0]; __syncthreads();
  float sum = 0.f;
  for (int i = tid; i < n; i += 256) sum += __expf(s[i] - mx) * mk[i];
  red[tid] = sum; __syncthreads();
  for (int stp = 128; stp > 0; stp >>= 1) { if (tid < stp) red[tid] += red[tid + stp]; __syncthreads(); }
  float denom = red[0] + 1e-6f;
  for (int i = tid; i < n; i += 256)
    att[st + (long)b * n + i] = __expf(s[i] - mx) * mk[i] / denom;
}

// ---------------------------------------------------------------------------
// weighted sum (grid.z = iteration; XBF: x is bf16) — r9-validated
// ---------------------------------------------------------------------------
template<int XBF>
__global__ __launch_bounds__(128) void wsum_kernel(
    const void* __restrict__ xp, const float* __restrict__ att,
    float* __restrict__ out, int n, int nsplit)
{
  int b = blockIdx.x;
  int sp = blockIdx.y;
  int it = blockIdx.z;
  int d = threadIdx.x;
  int chunk = n / nsplit;
  int t0 = sp * chunk, t1 = t0 + chunk;
  const float* ab = att + (long)it * gridDim.x * n + (long)b * n;
  float acc = 0.f;
  if (XBF) {
    const u16* xb = (const u16*)xp + (long)b * n * LT + d;
#pragma unroll 8
    for (int t = t0; t < t1; ++t) acc += bf2f(xb[(long)t * LT]) * ab[t];
  } else {
    const float* xb = (const float*)xp + (long)b * n * LT + d;
#pragma unroll 8
    for (int t = t0; t < t1; ++t) acc += xb[(long)t * LT] * ab[t];
  }
  atomicAdd(&out[(long)b * 512 + it * LT + d], acc);
}

__global__ __launch_bounds__(128) void assemble_v_kernel(
    const float* __restrict__ sf, const float* __restrict__ invT,
    const float* __restrict__ T, float* __restrict__ v)
{
  int b = blockIdx.x;
  int t = threadIdx.x;
  v[(long)b * DOUT + 128 + t] = sf[(long)b * LT + t];
  if (t == 0) { v[(long)b * DOUT + 384] = invT[b]; v[(long)b * DOUT + 385] = T[b]; }
}

// ---------------------------------------------------------------------------
extern "C" void kernel_launch(void* const* d_in, const int* in_sizes, int n_in,
                              void* d_out, int out_size, void* d_ws, size_t ws_size,
                              hipStream_t stream) {
  const long NB = (long)Bn * Nn;    // 16384
  const long LB = (long)Bn * Ln;    // 131072
  const long M1 = 1024 * 1024;

  const int*   atoms      = (const int*)d_in[0];
  const float* atoms_mask = (const float*)d_in[1];
  const int*   adj        = (const int*)d_in[2];
  const int*   amino      = (const int*)d_in[3];
  const float* amino_mask = (const float*)d_in[4];
  const float* fps        = (const float*)d_in[5];
  const float* invT       = (const float*)d_in[6];
  const float* Temp       = (const float*)d_in[7];
  const float* E_atom     = (const float*)d_in[8];
  const float* E_amino    = (const float*)d_in[9];
  const float* gatW       = (const float*)d_in[10];
  const float* gatA       = (const float*)d_in[11];
  const float* goW        = (const float*)d_in[12];
  const float* goA        = (const float*)d_in[13];
  const float* Wc_w       = (const float*)d_in[14];
  const float* Wc_b       = (const float*)d_in[15];
  const float* conv_k     = (const float*)d_in[16];
  const float* conv_b     = (const float*)d_in[17];
  const float* Wp_w       = (const float*)d_in[18];
  const float* Wp_b       = (const float*)d_in[19];
  const float* fp0        = (const float*)d_in[20];
  const float* fp1        = (const float*)d_in[21];
  const float* U          = (const float*)d_in[22];
  const float* t_c2p_w    = (const float*)d_in[23];
  const float* t_c2p_b    = (const float*)d_in[24];
  const float* t_p2c_w    = (const float*)d_in[25];
  const float* t_p2c_b    = (const float*)d_in[26];
  const float* bh_c_w     = (const float*)d_in[27];
  const float* bh_c_b     = (const float*)d_in[28];
  const float* bh_p_w     = (const float*)d_in[29];
  const float* bh_p_b     = (const float*)d_in[30];
  const float* ba_c_w     = (const float*)d_in[31];
  const float* ba_c_b     = (const float*)d_in[32];
  const float* ba_p_w     = (const float*)d_in[33];
  const float* ba_p_b     = (const float*)d_in[34];
  const float* comb_c_w   = (const float*)d_in[35];
  const float* comb_c_b   = (const float*)d_in[36];
  const float* comb_p_w   = (const float*)d_in[37];
  const float* comb_p_b   = (const float*)d_in[38];
  const float* Wout_w     = (const float*)d_in[39];
  const float* Wout_b     = (const float*)d_in[40];
  const float* out_w      = (const float*)d_in[41];
  const float* out_b      = (const float*)d_in[42];
  float* out = (float*)d_out;

  // ---------------- workspace layout (~98 MB) ----------------
  float* ws = (float*)d_ws;
  long off = 0;
  float* AV    = ws + off; off += NB * LT;          // 2M fp32
  u16*   PVbf  = (u16*)(ws + off); off += LB * LT / 2;
  float* SF    = ws + off; off += (long)Bn * LT;
  float* SFT   = ws + off; off += (long)Bn * LT;
  float* CF    = ws + off; off += (long)Bn * 512;
  float* PF    = ws + off; off += (long)Bn * 512;
  float* F1    = ws + off; off += 4 * NB;
  float* F2    = ws + off; off += 4 * NB;
  float* ATTA4 = ws + off; off += 4 * NB;
  float* ATTP4 = ws + off; off += 4 * LB;
  float* V0    = ws + off; off += (long)Bn * DOUT;
  float* V1    = ws + off; off += (long)Bn * DOUT;
  u64*   ADJB  = (u64*)(ws + off); off += NB * 4 * 2;   // [NB][4] u64
  float* WVEC  = ws + off; off += 2048;                 // 1536 used
  // weight cache (persistent)
  u16* WT = (u16*)(ws + off);
  long wo = 0;
  u16* gatW_t  = WT + wo; wo += 4L * 64 * 128;      // [256 n][128 k]
  u16* goW_t   = WT + wo; wo += 128L * 256;
  u16* T23     = WT + wo; wo += 23L * 16384;
  u16* fp0_t   = WT + wo; wo += 128L * 1024;
  u16* combc_t = WT + wo; wo += 128L * 512;
  u16* combp_t = WT + wo; wo += 128L * 512;
  off += (wo + 1) / 2;
  float* pk_a = ws + off; off += 2056;
  float* pk_p = ws + off; off += 2056;
  float* POOL = ws + off;                           // needs 16.78M floats
  u16* Wc_t   = T23;
  u16* Wp_t   = T23 + 16384;
  u16* fp1_t  = T23 + 2L * 16384;
  u16* U_t    = T23 + 3L * 16384;                   // 4 mats contiguous
  u16* wcat_a = T23 + 7L * 16384;                   // [bh_c(4) | t_c2p(4)]
  u16* wcat_p = T23 + 15L * 16384;                  // [bh_p(4) | t_p2c(4)]
  // pool aliases:
  float* AVE   = POOL;                              // [0,2M)
  u16*   WhT4  = (u16*)(POOL + 2 * M1);             // [b][256][256] u16 = [2M,4M)
  float* MH    = POOL + 4 * M1;                     // [4M,8.19M)
  u16*   WhT2  = (u16*)POOL;                        // [b][128][256] u16 = [0,1M)  (AVE dead)
  float* G2    = POOL + 2 * M1;                     // [2M,4M)  (WhT4 dead)
  float* PVA   = POOL;                              // CNN ping [0,8.39M)
  float* PVB   = POOL + 8 * M1;                     // CNN pong
  u16*   AVU4  = (u16*)POOL;                        // [NB][512] u16 = [0,4M)
  float* OUTP  = POOL + 4 * M1;                     // [8][LB]
  float* OUTA  = POOL + 5 * M1;                     // [8][NB]

  // ======================= weight prep =======================
  transp_kernel<<<dim3(32, 4), 256, 0, stream>>>(gatW, gatW_t, 128, 64);
  transp_kernel<<<dim3(128), 256, 0, stream>>>(goW, goW_t, 256, 128);
  transp_kernel<<<dim3(512), 256, 0, stream>>>(fp0, fp0_t, 1024, 128);
  transp_kernel<<<dim3(256), 256, 0, stream>>>(comb_c_w, combc_t, 512, 128);
  transp_kernel<<<dim3(256), 256, 0, stream>>>(comb_p_w, combp_t, 512, 128);
  {
    Ptr8 a1 = {{Wc_w, Wp_w, fp1, U, U + 16384, U + 32768, U + 49152, bh_c_w}};
    Ptr8 a2 = {{bh_c_w + 16384, bh_c_w + 32768, bh_c_w + 49152,
                t_c2p_w, t_c2p_w + 16384, t_c2p_w + 32768, t_c2p_w + 49152,
                bh_p_w}};
    Ptr8 a3 = {{bh_p_w + 16384, bh_p_w + 32768, bh_p_w + 49152,
                t_p2c_w, t_p2c_w + 16384, t_p2c_w + 32768, t_p2c_w + 49152,
                bh_p_w}};
    transp8_kernel<<<dim3(64, 8), 256, 0, stream>>>(a1, T23);
    transp8_kernel<<<dim3(64, 8), 256, 0, stream>>>(a2, T23 + 8L * 16384);
    transp8_kernel<<<dim3(64, 7), 256, 0, stream>>>(a3, T23 + 16L * 16384);
  }
  pack_kernel<<<dim3(9), 256, 0, stream>>>(bh_c_b, t_c2p_b, ba_c_w, ba_c_b,
                                           ba_p_w, bh_p_b, t_p2c_b, ba_p_b,
                                           pk_a, pk_p);
  packadj_kernel<<<dim3((unsigned)(NB * Nn / 256)), 256, 0, stream>>>(adj, ADJB);
  wvec_kernel<<<dim3(6), 256, 0, stream>>>(gatW, gatA, goW, goA, WVEC);

  // ======================= comp GAT (MFMA, bitmask) =======================
  embed_kernel<<<dim3((unsigned)((NB * CMP + 255) / 256)), 256, 0, stream>>>(
      atoms, E_atom, AVE, NB * CMP, CMP);
  mmx<0, 2>(stream, AVE, gatW_t, nullptr, WhT4, (int)NB, 256, 128, 128, 0, 0,
            256, 256L * 256, 256);
  favv_kernel<<<dim3((unsigned)(NB / 4)), 256, 0, stream>>>(AVE, WVEC, F1, F2, NB);
  gat3_kernel<GF><<<dim3(Nn / 32, Bn, 4), 256, 0, stream>>>(
      WhT4, 256L * 256, F1, F2, ADJB, MH, 256);
  mmx<0, 2>(stream, MH, goW_t, nullptr, WhT2, (int)NB, 128, 256, 256, 0, 0,
            256, 128L * 256, 256);
  fmh_kernel<<<dim3((unsigned)(NB / 4)), 256, 0, stream>>>(MH, WVEC + 1024, F1, F2, NB);
  gat3_kernel<CMP><<<dim3(Nn / 32, Bn, 1), 256, 0, stream>>>(
      WhT2, 128L * 256, F1, F2, ADJB, G2, 128);
  mmx<1, 0>(stream, G2, Wc_t, Wc_b, AV, (int)NB, 128, 128, 128, 128);

  // ======================= prot CNN (embed fused into conv1) ===============
  for (int c = 0; c < NCH; ++c) {
    long b0 = (long)c * CB;
    conv11e_kernel<<<dim3(Ln / 32, CB), 256, 0, stream>>>(
        amino + b0 * Ln, E_amino, conv_k + 0 * 121, conv_b + 0, PVA);
    conv11_kernel<<<dim3(Ln / 32, CB), 256, 0, stream>>>(PVA, conv_k + 1 * 121, conv_b + 1, PVB);
    conv11_kernel<<<dim3(Ln / 32, CB), 256, 0, stream>>>(PVB, conv_k + 2 * 121, conv_b + 2, PVA);
    mmx<1, 1>(stream, PVA, Wp_t, Wp_b, PVbf + b0 * Ln * 128,
              (int)((long)CB * Ln), 128, 128, 128, 128);
  }

  // ======================= fingerprint =======================
  mmx<2, 0>(stream, fps, fp0_t, nullptr, SFT, Bn, 128, 1024, 1024, 128);
  mmx<2, 0>(stream, SFT, fp1_t, nullptr, SF, Bn, 128, 128, 128, 128);

  // ======================= bidirectional attention =======================
  mmdot_kernel<1><<<dim3((unsigned)(LB / 128), 2), 256, 0, stream>>>(
      PVbf, wcat_p, pk_p, OUTP, LB);
  mmdot_kernel<0><<<dim3((unsigned)(NB / 128), 2), 256, 0, stream>>>(
      AV, wcat_a, pk_a, OUTA, NB);
  mmx<0, 1>(stream, AV, U_t, nullptr, AVU4, (int)NB, 512, 128, 128, 512);
  zero_kernel<<<dim3((unsigned)((2L * Bn * 512 + 255) / 256)), 256, 0, stream>>>(
      CF, 2L * Bn * 512);
  bidat_fused<<<dim3(Nn / 128, Bn, FLSP * 4), 256, 0, stream>>>(
      AVU4, PVbf, OUTP, OUTA, atoms_mask, amino_mask);
  mask_softmax_kernel<<<dim3(Bn, 4), 256, 0, stream>>>(OUTA, atoms_mask, ATTA4, Nn);
  mask_softmax_kernel<<<dim3(Bn, 4), 256, 0, stream>>>(OUTP, amino_mask, ATTP4, Ln);
  wsum_kernel<0><<<dim3(Bn, 8, 4), 128, 0, stream>>>(AV, ATTA4, CF, Nn, 8);
  wsum_kernel<1><<<dim3(Bn, 8, 4), 128, 0, stream>>>(PVbf, ATTP4, PF, Ln, 8);

  // ======================= head =======================
  mmx<0, 0>(stream, CF, combc_t, comb_c_b, V0, Bn, 128, 512, 512, DOUT, 0);
  mmx<0, 0>(stream, PF, combp_t, comb_p_b, V0, Bn, 128, 512, 512, DOUT, 256);
  assemble_v_kernel<<<Bn, 128, 0, stream>>>(SF, invT, Temp, V0);
  mm(stream, V0, Wout_w,                     Wout_b,            V1, Bn, DOUT, DOUT, DOUT, DOUT, DOUT, 0, 1);
  mm(stream, V1, Wout_w + (long)DOUT * DOUT, Wout_b + DOUT,     V0, Bn, DOUT, DOUT, DOUT, DOUT, DOUT, 0, 1);
  mm(stream, V0, Wout_w + 2L * DOUT * DOUT,  Wout_b + 2 * DOUT, V1, Bn, DOUT, DOUT, DOUT, DOUT, DOUT, 0, 1);
  mm(stream, V1, out_w, out_b, out, Bn, 1, DOUT, DOUT, 1, 1, 0, 0);
}